// Round 4
// baseline (1469.707 us; speedup 1.0000x reference)
//
#include <hip/hip_runtime.h>
#include <math.h>

#define T 1024
#define SEQ 512
#define BATCH 2
#define D 768
#define H 12
#define DH 64
#define DL 64
#define E 8
#define HID 3072
#define HC 512   // HID chunk for MoE g materialization

// ---------------- rmsnorm ----------------
__global__ void rmsnorm_kernel(const float* __restrict__ x, const float* __restrict__ w,
                               float* __restrict__ out) {
    int t = blockIdx.x;
    int tid = threadIdx.x; // 256
    const float* xr = x + (size_t)t * D;
    float s = 0.f;
    for (int i = tid; i < D; i += 256) { float v = xr[i]; s += v * v; }
    __shared__ float red[256];
    red[tid] = s; __syncthreads();
    for (int o = 128; o > 0; o >>= 1) { if (tid < o) red[tid] += red[tid + o]; __syncthreads(); }
    float scale = 1.0f / sqrtf(red[0] / (float)D + 1e-6f);
    for (int i = tid; i < D; i += 256) out[(size_t)t * D + i] = xr[i] * scale * w[i];
}

// ---------------- generic fp32 GEMM: C[M,N] = A[M,K]@B[K,N] (+ residual R) ----------------
template<bool RES>
__global__ void gemm64(const float* __restrict__ A, const float* __restrict__ B,
                       const float* __restrict__ Rp, float* __restrict__ C,
                       int M, int N, int K) {
    __shared__ float As[16][65];
    __shared__ float Bs[16][68];
    int tid = threadIdx.x;
    int mb = blockIdx.y * 64, nb = blockIdx.x * 64;
    int tr = tid >> 4, tc = tid & 15;
    int aRow = tid >> 2, aCol = (tid & 3) * 4;
    int bRow = tid >> 4, bCol = (tid & 15) * 4;
    float acc[4][4] = {};
    for (int k0 = 0; k0 < K; k0 += 16) {
        float4 av = make_float4(0.f, 0.f, 0.f, 0.f);
        int ar = mb + aRow;
        if (ar < M) av = *(const float4*)(A + (size_t)ar * K + k0 + aCol);
        As[aCol + 0][aRow] = av.x; As[aCol + 1][aRow] = av.y;
        As[aCol + 2][aRow] = av.z; As[aCol + 3][aRow] = av.w;
        float4 bv = make_float4(0.f, 0.f, 0.f, 0.f);
        int bc = nb + bCol;
        if (bc < N) bv = *(const float4*)(B + (size_t)(k0 + bRow) * N + bc);
        *(float4*)&Bs[bRow][bCol] = bv;
        __syncthreads();
#pragma unroll
        for (int kk = 0; kk < 16; kk++) {
            float a[4], b[4];
#pragma unroll
            for (int i = 0; i < 4; i++) a[i] = As[kk][tr * 4 + i];
#pragma unroll
            for (int j = 0; j < 4; j++) b[j] = Bs[kk][tc * 4 + j];
#pragma unroll
            for (int i = 0; i < 4; i++)
#pragma unroll
                for (int j = 0; j < 4; j++) acc[i][j] += a[i] * b[j];
        }
        __syncthreads();
    }
#pragma unroll
    for (int i = 0; i < 4; i++) {
        int r = mb + tr * 4 + i;
        if (r >= M) continue;
#pragma unroll
        for (int j = 0; j < 4; j++) {
            int cn = nb + tc * 4 + j;
            if (cn >= N) continue;
            float val = acc[i][j];
            if (RES) val += Rp[(size_t)r * N + cn];
            C[(size_t)r * N + cn] = val;
        }
    }
}

// ---------------- RoPE (in-place on q and k) ----------------
__global__ void rope_kernel(float* __restrict__ qb, float* __restrict__ kb,
                            const int* __restrict__ spp) {
    int p = blockIdx.x * 256 + threadIdx.x; // T*H*32
    if (p >= T * H * 32) return;
    int i = p & 31;
    int rem = p >> 5;
    int h = rem % H;
    int ts = rem / H;
    int s = ts % SEQ;
    float invf = powf(10000.0f, -(float)(2 * i) / 64.0f);
    float ang = (float)(s + spp[0]) * invf;
    float c = cosf(ang), sn = sinf(ang);
    size_t base = (size_t)ts * D + h * DH;
    float x1 = qb[base + i], x2 = qb[base + 32 + i];
    qb[base + i] = x1 * c - x2 * sn;
    qb[base + 32 + i] = x1 * sn + x2 * c;
    x1 = kb[base + i]; x2 = kb[base + 32 + i];
    kb[base + i] = x1 * c - x2 * sn;
    kb[base + 32 + i] = x1 * sn + x2 * c;
}

// ---------------- causal attention, one block (64 thr) per (b,h,q-row) ----------------
__global__ void attn_kernel(const float* __restrict__ q, const float* __restrict__ k,
                            const float* __restrict__ v, float* __restrict__ a) {
    int idx = blockIdx.x;
    int qs = idx % SEQ;
    int bh = idx / SEQ;
    int h = bh % H;
    int b = bh / H;
    int tid = threadIdx.x; // 64
    __shared__ float ql[64];
    __shared__ float p[SEQ];
    const float* qrow = q + ((size_t)(b * SEQ + qs)) * D + h * DH;
    ql[tid] = qrow[tid];
    __syncthreads();
    int nk = qs + 1;
    float lmax = -1e30f;
    float sc[8];
#pragma unroll
    for (int c = 0; c < 8; c++) {
        int kk = tid + c * 64;
        float acc = -1e30f;
        if (kk < nk) {
            const float* krow = k + ((size_t)(b * SEQ + kk)) * D + h * DH;
            float d0 = 0.f;
#pragma unroll
            for (int d = 0; d < 64; d++) d0 += ql[d] * krow[d];
            acc = d0 * 0.125f;
            lmax = fmaxf(lmax, acc);
        }
        sc[c] = acc;
    }
#pragma unroll
    for (int o = 32; o > 0; o >>= 1) lmax = fmaxf(lmax, __shfl_xor(lmax, o));
    float lsum = 0.f;
#pragma unroll
    for (int c = 0; c < 8; c++) {
        int kk = tid + c * 64;
        if (kk < nk) {
            float e = expf(sc[c] - lmax);
            p[kk] = e;
            lsum += e;
        }
    }
#pragma unroll
    for (int o = 32; o > 0; o >>= 1) lsum += __shfl_xor(lsum, o);
    __syncthreads();
    float inv = 1.0f / lsum;
    float acc = 0.f;
    for (int kk = 0; kk < nk; kk++) {
        acc += p[kk] * v[((size_t)(b * SEQ + kk)) * D + h * DH + tid];
    }
    a[((size_t)(b * SEQ + qs)) * D + h * DH + tid] = acc * inv;
}

// ---------------- routing: logits -> softmax -> top2 -> lists ----------------
__global__ void routing_kernel(const float* __restrict__ h2, const float* __restrict__ gw,
                               float* __restrict__ probs, int* __restrict__ list,
                               int* __restrict__ counts, float* __restrict__ wtok) {
    int t = blockIdx.x;
    int tid = threadIdx.x; // 64
    __shared__ float part[64][8];
    float l[8] = {0.f, 0.f, 0.f, 0.f, 0.f, 0.f, 0.f, 0.f};
    const float* hr = h2 + (size_t)t * D;
    for (int i = tid; i < D; i += 64) {
        float hv = hr[i];
        const float* g = gw + (size_t)i * E;
#pragma unroll
        for (int e = 0; e < 8; e++) l[e] += hv * g[e];
    }
#pragma unroll
    for (int e = 0; e < 8; e++) part[tid][e] = l[e];
    __syncthreads();
    if (tid == 0) {
        float lg[8];
#pragma unroll
        for (int e = 0; e < 8; e++) {
            float s = 0.f;
            for (int j = 0; j < 64; j++) s += part[j][e];
            lg[e] = s;
        }
        float m = lg[0];
#pragma unroll
        for (int e = 1; e < 8; e++) m = fmaxf(m, lg[e]);
        float se = 0.f;
        float pr[8];
#pragma unroll
        for (int e = 0; e < 8; e++) { pr[e] = expf(lg[e] - m); se += pr[e]; }
#pragma unroll
        for (int e = 0; e < 8; e++) { pr[e] /= se; probs[t * 8 + e] = pr[e]; }
        int i0 = 0;
#pragma unroll
        for (int e = 1; e < 8; e++) if (pr[e] > pr[i0]) i0 = e;
        int i1 = -1;
#pragma unroll
        for (int e = 0; e < 8; e++) {
            if (e == i0) continue;
            if (i1 < 0 || pr[e] > pr[i1]) i1 = e;
        }
        float w0 = pr[i0], w1 = pr[i1];
        float wsum = w0 + w1;
        wtok[t * 2 + 0] = w0 / wsum;
        wtok[t * 2 + 1] = w1 / wsum;
        int p0 = atomicAdd(&counts[i0], 1); list[i0 * T + p0] = t * 2 + 0;
        int p1 = atomicAdd(&counts[i1], 1); list[i1 * T + p1] = t * 2 + 1;
    }
}

// ---------------- aux loss (deterministic single-block reduce) ----------------
__global__ void aux_kernel(const float* __restrict__ probs, const int* __restrict__ counts,
                           float* __restrict__ out_aux) {
    int tid = threadIdx.x;
    __shared__ float ps[8];
    if (tid < 8) {
        float s = 0.f;
        for (int t = 0; t < T; t++) s += probs[t * 8 + tid];
        ps[tid] = s;
    }
    __syncthreads();
    if (tid == 0) {
        float aux = 0.f;
        for (int e = 0; e < 8; e++) {
            float f = (float)counts[e] / (float)T;
            float P = ps[e] / (float)T;
            aux += f * P;
        }
        out_aux[0] = (float)E * aux;
    }
}

// ---- MoE up (chunked over HID): gchunk[pid][0..HC) = silu(h2@w1[:, cols]) * (h2@w3[:, cols])
__global__ void moe_up(const float* __restrict__ h2, const float* __restrict__ w1,
                       const float* __restrict__ w3, const int* __restrict__ list,
                       const int* __restrict__ counts, float* __restrict__ g, int c0) {
    int e = blockIdx.z;
    int n = counts[e];
    int mb = blockIdx.y * 64;
    if (mb >= n) return;
    int nb = blockIdx.x * 64;           // column within chunk
    const float* B1 = w1 + (size_t)e * D * HID + c0;
    const float* B3 = w3 + (size_t)e * D * HID + c0;
    __shared__ float As[16][65];
    __shared__ float B1s[16][68];
    __shared__ float B3s[16][68];
    __shared__ int rowtok[64];
    __shared__ int rowpid[64];
    int tid = threadIdx.x;
    if (tid < 64) {
        int r = mb + tid;
        int pid = (r < n) ? list[e * T + r] : 0;
        rowpid[tid] = pid;
        rowtok[tid] = pid >> 1;
    }
    __syncthreads();
    float acc1[4][4] = {};
    float acc3[4][4] = {};
    int aRow = tid >> 2, aCol = (tid & 3) * 4;
    int bRow = tid >> 4, bCol = (tid & 15) * 4;
    int tr = tid >> 4, tc = tid & 15;
    for (int k0 = 0; k0 < D; k0 += 16) {
        int tok = rowtok[aRow];
        float4 av = *(const float4*)(h2 + (size_t)tok * D + k0 + aCol);
        As[aCol + 0][aRow] = av.x; As[aCol + 1][aRow] = av.y;
        As[aCol + 2][aRow] = av.z; As[aCol + 3][aRow] = av.w;
        float4 b1 = *(const float4*)(B1 + (size_t)(k0 + bRow) * HID + nb + bCol);
        float4 b3 = *(const float4*)(B3 + (size_t)(k0 + bRow) * HID + nb + bCol);
        *(float4*)&B1s[bRow][bCol] = b1;
        *(float4*)&B3s[bRow][bCol] = b3;
        __syncthreads();
#pragma unroll
        for (int kk = 0; kk < 16; kk++) {
            float a[4], b1v[4], b3v[4];
#pragma unroll
            for (int i = 0; i < 4; i++) a[i] = As[kk][tr * 4 + i];
#pragma unroll
            for (int j = 0; j < 4; j++) { b1v[j] = B1s[kk][tc * 4 + j]; b3v[j] = B3s[kk][tc * 4 + j]; }
#pragma unroll
            for (int i = 0; i < 4; i++)
#pragma unroll
                for (int j = 0; j < 4; j++) {
                    acc1[i][j] += a[i] * b1v[j];
                    acc3[i][j] += a[i] * b3v[j];
                }
        }
        __syncthreads();
    }
#pragma unroll
    for (int i = 0; i < 4; i++) {
        int r = mb + tr * 4 + i;
        if (r >= n) continue;
        int pid = rowpid[tr * 4 + i];
#pragma unroll
        for (int j = 0; j < 4; j++) {
            float x1v = acc1[i][j];
            float sil = x1v / (1.0f + expf(-x1v));
            g[(size_t)pid * HC + nb + tc * 4 + j] = sil * acc3[i][j];
        }
    }
}

// ---- MoE down (chunked): yp[pid] (+)= gchunk[pid] @ w2[e][c0:c0+HC, :]
template<bool FIRST>
__global__ void moe_down(const float* __restrict__ g, const float* __restrict__ w2,
                         const int* __restrict__ list, const int* __restrict__ counts,
                         float* __restrict__ yp, int c0) {
    int e = blockIdx.z;
    int n = counts[e];
    int mb = blockIdx.y * 64;
    if (mb >= n) return;
    int nb = blockIdx.x * 64;
    const float* B = w2 + (size_t)e * HID * D + (size_t)c0 * D;
    __shared__ float As[16][65];
    __shared__ float Bs[16][68];
    __shared__ int rowpid[64];
    int tid = threadIdx.x;
    if (tid < 64) {
        int r = mb + tid;
        rowpid[tid] = (r < n) ? list[e * T + r] : 0;
    }
    __syncthreads();
    float acc[4][4] = {};
    int aRow = tid >> 2, aCol = (tid & 3) * 4;
    int bRow = tid >> 4, bCol = (tid & 15) * 4;
    int tr = tid >> 4, tc = tid & 15;
    for (int k0 = 0; k0 < HC; k0 += 16) {
        int pid = rowpid[aRow];
        float4 av = *(const float4*)(g + (size_t)pid * HC + k0 + aCol);
        As[aCol + 0][aRow] = av.x; As[aCol + 1][aRow] = av.y;
        As[aCol + 2][aRow] = av.z; As[aCol + 3][aRow] = av.w;
        float4 bv = *(const float4*)(B + (size_t)(k0 + bRow) * D + nb + bCol);
        *(float4*)&Bs[bRow][bCol] = bv;
        __syncthreads();
#pragma unroll
        for (int kk = 0; kk < 16; kk++) {
            float a[4], b[4];
#pragma unroll
            for (int i = 0; i < 4; i++) a[i] = As[kk][tr * 4 + i];
#pragma unroll
            for (int j = 0; j < 4; j++) b[j] = Bs[kk][tc * 4 + j];
#pragma unroll
            for (int i = 0; i < 4; i++)
#pragma unroll
                for (int j = 0; j < 4; j++) acc[i][j] += a[i] * b[j];
        }
        __syncthreads();
    }
#pragma unroll
    for (int i = 0; i < 4; i++) {
        int r = mb + tr * 4 + i;
        if (r >= n) continue;
        int pid = rowpid[tr * 4 + i];
#pragma unroll
        for (int j = 0; j < 4; j++) {
            size_t o = (size_t)pid * D + nb + tc * 4 + j;
            if (FIRST) yp[o] = acc[i][j];
            else       yp[o] += acc[i][j];
        }
    }
}

// ---------------- final combine: out = x1(out) + w0*yp[2t] + w1*yp[2t+1] ----------------
__global__ void combine_kernel(const float* __restrict__ yp, const float* __restrict__ wtok,
                               float* __restrict__ out) {
    int idx = blockIdx.x * 256 + threadIdx.x; // T * (D/4)
    if (idx >= T * (D / 4)) return;
    int t = idx / (D / 4);
    int d4 = idx % (D / 4);
    float4 a = ((const float4*)(out + (size_t)t * D))[d4];
    float4 y0 = ((const float4*)(yp + (size_t)(2 * t) * D))[d4];
    float4 y1 = ((const float4*)(yp + (size_t)(2 * t + 1) * D))[d4];
    float w0 = wtok[2 * t], w1 = wtok[2 * t + 1];
    a.x += w0 * y0.x + w1 * y1.x;
    a.y += w0 * y0.y + w1 * y1.y;
    a.z += w0 * y0.z + w1 * y1.z;
    a.w += w0 * y0.w + w1 * y1.w;
    ((float4*)(out + (size_t)t * D))[d4] = a;
}

extern "C" void kernel_launch(void* const* d_in, const int* in_sizes, int n_in,
                              void* d_out, int out_size, void* d_ws, size_t ws_size,
                              hipStream_t stream) {
    const float* x    = (const float*)d_in[0];
    const float* n1w  = (const float*)d_in[1];
    const float* n2w  = (const float*)d_in[2];
    const float* wq   = (const float*)d_in[3];
    const float* wdkv = (const float*)d_in[4];
    const float* wuk  = (const float*)d_in[5];
    const float* wuv  = (const float*)d_in[6];
    const float* wo   = (const float*)d_in[7];
    const float* gw   = (const float*)d_in[8];
    const float* w1   = (const float*)d_in[9];
    const float* w2   = (const float*)d_in[10];
    const float* w3   = (const float*)d_in[11];
    const int*   sp   = (const int*)d_in[12];
    float* out = (float*)d_out;

    // ws layout (floats). Total ~17.1 MB — aggressive reuse to stay within ws_size.
    float* ws = (float*)d_ws;
    float* A_  = ws + 0;                 // 786432: qb, later h2b
    float* B_  = ws + 786432;            // 786432: kb, later yp[0..]
    float* C_  = ws + 1572864;           // 786432: vb, later yp[..]
    float* Dd  = ws + 2359296;           // 786432: h, later ab
    float* cb  = ws + 3145728;           // 65536
    float* probs = ws + 3211264;         // 8192
    float* wtok  = ws + 3219456;         // 2048
    int*   list  = (int*)(ws + 3221504); // 8192 ints
    int*   counts= (int*)(ws + 3229696); // 16 ints
    float* gchunk= ws + 3229712;         // 2T*HC = 2048*512 = 1048576
    float* yp = B_;                      // 2T*D = 1572864 (B_ and C_ contiguous)

    hipMemsetAsync(counts, 0, 16 * sizeof(int), stream);

    // ---- attention ----
    rmsnorm_kernel<<<T, 256, 0, stream>>>(x, n1w, Dd);                                   // h
    gemm64<false><<<dim3(D / 64, T / 64), 256, 0, stream>>>(Dd, wq, nullptr, A_, T, D, D);   // qb
    gemm64<false><<<dim3(1, T / 64), 256, 0, stream>>>(Dd, wdkv, nullptr, cb, T, DL, D);     // c
    gemm64<false><<<dim3(D / 64, T / 64), 256, 0, stream>>>(cb, wuk, nullptr, B_, T, D, DL); // kb
    gemm64<false><<<dim3(D / 64, T / 64), 256, 0, stream>>>(cb, wuv, nullptr, C_, T, D, DL); // vb
    rope_kernel<<<(T * H * 32 + 255) / 256, 256, 0, stream>>>(A_, B_, sp);
    attn_kernel<<<BATCH * H * SEQ, 64, 0, stream>>>(A_, B_, C_, Dd);                     // ab (Dd reused)
    gemm64<true><<<dim3(D / 64, T / 64), 256, 0, stream>>>(Dd, wo, x, out, T, D, D);     // x1 staged in out

    // ---- MoE ----
    rmsnorm_kernel<<<T, 256, 0, stream>>>(out, n2w, A_);                                 // h2 (A_ reused)
    routing_kernel<<<T, 64, 0, stream>>>(A_, gw, probs, list, counts, wtok);
    aux_kernel<<<1, 256, 0, stream>>>(probs, counts, out + (out_size - 1));
    for (int c0 = 0; c0 < HID; c0 += HC) {
        moe_up<<<dim3(HC / 64, T / 64, E), 256, 0, stream>>>(A_, w1, w3, list, counts, gchunk, c0);
        if (c0 == 0)
            moe_down<true><<<dim3(D / 64, T / 64, E), 256, 0, stream>>>(gchunk, w2, list, counts, yp, c0);
        else
            moe_down<false><<<dim3(D / 64, T / 64, E), 256, 0, stream>>>(gchunk, w2, list, counts, yp, c0);
    }
    combine_kernel<<<(T * (D / 4) + 255) / 256, 256, 0, stream>>>(yp, wtok, out);
}

// Round 5
// 778.823 us; speedup vs baseline: 1.8871x; 1.8871x over previous
//
#include <hip/hip_runtime.h>
#include <math.h>

#define T 1024
#define SEQ 512
#define BATCH 2
#define D 768
#define H 12
#define DH 64
#define DL 64
#define E 8
#define HID 3072
#define HC 512   // HID chunk for MoE g materialization

typedef __attribute__((ext_vector_type(8))) short bf16x8;
typedef __attribute__((ext_vector_type(4))) float f32x4;

// fp32 -> bf16 round-to-nearest-even
__device__ inline short f2bf(float f) {
    unsigned u = __float_as_uint(f);
    unsigned r = u + 0x7fff + ((u >> 16) & 1);
    return (short)(r >> 16);
}

// swizzled LDS index (shorts): tile stored [row][k], 64 k per row.
// XOR row bits into bit3..5 of k-index => byte-bit4..6 (breaks stride-128B bank conflict)
__device__ inline int swz(int row, int k) { return (row * 64 + k) ^ ((row & 7) << 3); }

// ---------------- rmsnorm ----------------
__global__ void rmsnorm_kernel(const float* __restrict__ x, const float* __restrict__ w,
                               float* __restrict__ out) {
    int t = blockIdx.x;
    int tid = threadIdx.x; // 256
    const float* xr = x + (size_t)t * D;
    float s = 0.f;
    for (int i = tid; i < D; i += 256) { float v = xr[i]; s += v * v; }
    __shared__ float red[256];
    red[tid] = s; __syncthreads();
    for (int o = 128; o > 0; o >>= 1) { if (tid < o) red[tid] += red[tid + o]; __syncthreads(); }
    float scale = 1.0f / sqrtf(red[0] / (float)D + 1e-6f);
    for (int i = tid; i < D; i += 256) out[(size_t)t * D + i] = xr[i] * scale * w[i];
}

// ---------------- generic fp32 GEMM (attention-side, unchanged) ----------------
template<bool RES>
__global__ void gemm64(const float* __restrict__ A, const float* __restrict__ B,
                       const float* __restrict__ Rp, float* __restrict__ C,
                       int M, int N, int K) {
    __shared__ float As[16][65];
    __shared__ float Bs[16][68];
    int tid = threadIdx.x;
    int mb = blockIdx.y * 64, nb = blockIdx.x * 64;
    int tr = tid >> 4, tc = tid & 15;
    int aRow = tid >> 2, aCol = (tid & 3) * 4;
    int bRow = tid >> 4, bCol = (tid & 15) * 4;
    float acc[4][4] = {};
    for (int k0 = 0; k0 < K; k0 += 16) {
        float4 av = make_float4(0.f, 0.f, 0.f, 0.f);
        int ar = mb + aRow;
        if (ar < M) av = *(const float4*)(A + (size_t)ar * K + k0 + aCol);
        As[aCol + 0][aRow] = av.x; As[aCol + 1][aRow] = av.y;
        As[aCol + 2][aRow] = av.z; As[aCol + 3][aRow] = av.w;
        float4 bv = make_float4(0.f, 0.f, 0.f, 0.f);
        int bc = nb + bCol;
        if (bc < N) bv = *(const float4*)(B + (size_t)(k0 + bRow) * N + bc);
        *(float4*)&Bs[bRow][bCol] = bv;
        __syncthreads();
#pragma unroll
        for (int kk = 0; kk < 16; kk++) {
            float a[4], b[4];
#pragma unroll
            for (int i = 0; i < 4; i++) a[i] = As[kk][tr * 4 + i];
#pragma unroll
            for (int j = 0; j < 4; j++) b[j] = Bs[kk][tc * 4 + j];
#pragma unroll
            for (int i = 0; i < 4; i++)
#pragma unroll
                for (int j = 0; j < 4; j++) acc[i][j] += a[i] * b[j];
        }
        __syncthreads();
    }
#pragma unroll
    for (int i = 0; i < 4; i++) {
        int r = mb + tr * 4 + i;
        if (r >= M) continue;
#pragma unroll
        for (int j = 0; j < 4; j++) {
            int cn = nb + tc * 4 + j;
            if (cn >= N) continue;
            float val = acc[i][j];
            if (RES) val += Rp[(size_t)r * N + cn];
            C[(size_t)r * N + cn] = val;
        }
    }
}

// ---------------- RoPE (in-place on q and k) ----------------
__global__ void rope_kernel(float* __restrict__ qb, float* __restrict__ kb,
                            const int* __restrict__ spp) {
    int p = blockIdx.x * 256 + threadIdx.x; // T*H*32
    if (p >= T * H * 32) return;
    int i = p & 31;
    int rem = p >> 5;
    int h = rem % H;
    int ts = rem / H;
    int s = ts % SEQ;
    float invf = powf(10000.0f, -(float)(2 * i) / 64.0f);
    float ang = (float)(s + spp[0]) * invf;
    float c = cosf(ang), sn = sinf(ang);
    size_t base = (size_t)ts * D + h * DH;
    float x1 = qb[base + i], x2 = qb[base + 32 + i];
    qb[base + i] = x1 * c - x2 * sn;
    qb[base + 32 + i] = x1 * sn + x2 * c;
    x1 = kb[base + i]; x2 = kb[base + 32 + i];
    kb[base + i] = x1 * c - x2 * sn;
    kb[base + 32 + i] = x1 * sn + x2 * c;
}

// ---------------- causal attention (unchanged this round) ----------------
__global__ void attn_kernel(const float* __restrict__ q, const float* __restrict__ k,
                            const float* __restrict__ v, float* __restrict__ a) {
    int idx = blockIdx.x;
    int qs = idx % SEQ;
    int bh = idx / SEQ;
    int h = bh % H;
    int b = bh / H;
    int tid = threadIdx.x; // 64
    __shared__ float ql[64];
    __shared__ float p[SEQ];
    const float* qrow = q + ((size_t)(b * SEQ + qs)) * D + h * DH;
    ql[tid] = qrow[tid];
    __syncthreads();
    int nk = qs + 1;
    float lmax = -1e30f;
    float sc[8];
#pragma unroll
    for (int c = 0; c < 8; c++) {
        int kk = tid + c * 64;
        float acc = -1e30f;
        if (kk < nk) {
            const float* krow = k + ((size_t)(b * SEQ + kk)) * D + h * DH;
            float d0 = 0.f;
#pragma unroll
            for (int d = 0; d < 64; d++) d0 += ql[d] * krow[d];
            acc = d0 * 0.125f;
            lmax = fmaxf(lmax, acc);
        }
        sc[c] = acc;
    }
#pragma unroll
    for (int o = 32; o > 0; o >>= 1) lmax = fmaxf(lmax, __shfl_xor(lmax, o));
    float lsum = 0.f;
#pragma unroll
    for (int c = 0; c < 8; c++) {
        int kk = tid + c * 64;
        if (kk < nk) {
            float e = expf(sc[c] - lmax);
            p[kk] = e;
            lsum += e;
        }
    }
#pragma unroll
    for (int o = 32; o > 0; o >>= 1) lsum += __shfl_xor(lsum, o);
    __syncthreads();
    float inv = 1.0f / lsum;
    float acc = 0.f;
    for (int kk = 0; kk < nk; kk++) {
        acc += p[kk] * v[((size_t)(b * SEQ + kk)) * D + h * DH + tid];
    }
    a[((size_t)(b * SEQ + qs)) * D + h * DH + tid] = acc * inv;
}

// ---------------- routing ----------------
__global__ void routing_kernel(const float* __restrict__ h2, const float* __restrict__ gw,
                               float* __restrict__ probs, int* __restrict__ list,
                               int* __restrict__ counts, float* __restrict__ wtok) {
    int t = blockIdx.x;
    int tid = threadIdx.x; // 64
    __shared__ float part[64][8];
    float l[8] = {0.f, 0.f, 0.f, 0.f, 0.f, 0.f, 0.f, 0.f};
    const float* hr = h2 + (size_t)t * D;
    for (int i = tid; i < D; i += 64) {
        float hv = hr[i];
        const float* g = gw + (size_t)i * E;
#pragma unroll
        for (int e = 0; e < 8; e++) l[e] += hv * g[e];
    }
#pragma unroll
    for (int e = 0; e < 8; e++) part[tid][e] = l[e];
    __syncthreads();
    if (tid == 0) {
        float lg[8];
#pragma unroll
        for (int e = 0; e < 8; e++) {
            float s = 0.f;
            for (int j = 0; j < 64; j++) s += part[j][e];
            lg[e] = s;
        }
        float m = lg[0];
#pragma unroll
        for (int e = 1; e < 8; e++) m = fmaxf(m, lg[e]);
        float se = 0.f;
        float pr[8];
#pragma unroll
        for (int e = 0; e < 8; e++) { pr[e] = expf(lg[e] - m); se += pr[e]; }
#pragma unroll
        for (int e = 0; e < 8; e++) { pr[e] /= se; probs[t * 8 + e] = pr[e]; }
        int i0 = 0;
#pragma unroll
        for (int e = 1; e < 8; e++) if (pr[e] > pr[i0]) i0 = e;
        int i1 = -1;
#pragma unroll
        for (int e = 0; e < 8; e++) {
            if (e == i0) continue;
            if (i1 < 0 || pr[e] > pr[i1]) i1 = e;
        }
        float w0 = pr[i0], w1 = pr[i1];
        float wsum = w0 + w1;
        wtok[t * 2 + 0] = w0 / wsum;
        wtok[t * 2 + 1] = w1 / wsum;
        int p0 = atomicAdd(&counts[i0], 1); list[i0 * T + p0] = t * 2 + 0;
        int p1 = atomicAdd(&counts[i1], 1); list[i1 * T + p1] = t * 2 + 1;
    }
}

// ---------------- aux loss ----------------
__global__ void aux_kernel(const float* __restrict__ probs, const int* __restrict__ counts,
                           float* __restrict__ out_aux) {
    int tid = threadIdx.x;
    __shared__ float ps[8];
    if (tid < 8) {
        float s = 0.f;
        for (int t = 0; t < T; t++) s += probs[t * 8 + tid];
        ps[tid] = s;
    }
    __syncthreads();
    if (tid == 0) {
        float aux = 0.f;
        for (int e = 0; e < 8; e++) {
            float f = (float)counts[e] / (float)T;
            float P = ps[e] / (float)T;
            aux += f * P;
        }
        out_aux[0] = (float)E * aux;
    }
}

// ---- MoE up, MFMA bf16: g[pid][HC cols] = silu(h2@w1) * (h2@w3), fp32 weights converted in staging
__global__ __launch_bounds__(256) void moe_up_mfma(
    const float* __restrict__ h2, const float* __restrict__ w1, const float* __restrict__ w3,
    const int* __restrict__ list, const int* __restrict__ counts,
    short* __restrict__ g, int c0) {
    int e = blockIdx.z;
    int n = counts[e];
    int mb = blockIdx.y * 64;
    if (mb >= n) return;
    int nb = blockIdx.x * 64;  // col within chunk
    const float* B1g = w1 + (size_t)e * D * HID + (c0 + nb);
    const float* B3g = w3 + (size_t)e * D * HID + (c0 + nb);
    __shared__ short As[64 * 64];   // [m][k] swizzled
    __shared__ short B1s[64 * 64];  // [n][k] swizzled (transposed)
    __shared__ short B3s[64 * 64];
    __shared__ int rowpid[64];
    __shared__ int rowtok[64];
    int tid = threadIdx.x;
    int lane = tid & 63, wave = tid >> 6;
    int wr = wave >> 1, wc = wave & 1;
    if (tid < 64) {
        int r = mb + tid;
        int pid = (r < n) ? list[e * T + r] : list[e * T];
        rowpid[tid] = pid;
        rowtok[tid] = pid >> 1;
    }
    __syncthreads();

    f32x4 acc1[2][2] = {};
    f32x4 acc3[2][2] = {};
    int ar = tid >> 2, ac = (tid & 3) * 16;
    const float* Arow = h2 + (size_t)rowtok[ar] * D + ac;

    for (int k0 = 0; k0 < D; k0 += 64) {
        // stage A (64x64 fp32 -> bf16)
#pragma unroll
        for (int j = 0; j < 4; j++) {
            float4 v = *(const float4*)(Arow + k0 + j * 4);
            short4 s4 = make_short4(f2bf(v.x), f2bf(v.y), f2bf(v.z), f2bf(v.w));
            *(short4*)&As[swz(ar, ac + j * 4)] = s4;
        }
        // stage B1/B3 transposed: [k][n] global -> [n][k] LDS
#pragma unroll
        for (int i = 0; i < 4; i++) {
            int idx = tid + i * 256;
            int kr = idx >> 4, n0 = (idx & 15) * 4;
            float4 v1 = *(const float4*)(B1g + (size_t)(k0 + kr) * HID + n0);
            float4 v3 = *(const float4*)(B3g + (size_t)(k0 + kr) * HID + n0);
            B1s[swz(n0 + 0, kr)] = f2bf(v1.x); B1s[swz(n0 + 1, kr)] = f2bf(v1.y);
            B1s[swz(n0 + 2, kr)] = f2bf(v1.z); B1s[swz(n0 + 3, kr)] = f2bf(v1.w);
            B3s[swz(n0 + 0, kr)] = f2bf(v3.x); B3s[swz(n0 + 1, kr)] = f2bf(v3.y);
            B3s[swz(n0 + 2, kr)] = f2bf(v3.z); B3s[swz(n0 + 3, kr)] = f2bf(v3.w);
        }
        __syncthreads();
#pragma unroll
        for (int kk = 0; kk < 64; kk += 32) {
            int krd = kk + 8 * (lane >> 4);
            bf16x8 a0  = *(const bf16x8*)&As[swz(wr * 32 + (lane & 15), krd)];
            bf16x8 a1  = *(const bf16x8*)&As[swz(wr * 32 + 16 + (lane & 15), krd)];
            bf16x8 b10 = *(const bf16x8*)&B1s[swz(wc * 32 + (lane & 15), krd)];
            bf16x8 b11 = *(const bf16x8*)&B1s[swz(wc * 32 + 16 + (lane & 15), krd)];
            bf16x8 b30 = *(const bf16x8*)&B3s[swz(wc * 32 + (lane & 15), krd)];
            bf16x8 b31 = *(const bf16x8*)&B3s[swz(wc * 32 + 16 + (lane & 15), krd)];
            acc1[0][0] = __builtin_amdgcn_mfma_f32_16x16x32_bf16(a0, b10, acc1[0][0], 0, 0, 0);
            acc1[0][1] = __builtin_amdgcn_mfma_f32_16x16x32_bf16(a0, b11, acc1[0][1], 0, 0, 0);
            acc1[1][0] = __builtin_amdgcn_mfma_f32_16x16x32_bf16(a1, b10, acc1[1][0], 0, 0, 0);
            acc1[1][1] = __builtin_amdgcn_mfma_f32_16x16x32_bf16(a1, b11, acc1[1][1], 0, 0, 0);
            acc3[0][0] = __builtin_amdgcn_mfma_f32_16x16x32_bf16(a0, b30, acc3[0][0], 0, 0, 0);
            acc3[0][1] = __builtin_amdgcn_mfma_f32_16x16x32_bf16(a0, b31, acc3[0][1], 0, 0, 0);
            acc3[1][0] = __builtin_amdgcn_mfma_f32_16x16x32_bf16(a1, b30, acc3[1][0], 0, 0, 0);
            acc3[1][1] = __builtin_amdgcn_mfma_f32_16x16x32_bf16(a1, b31, acc3[1][1], 0, 0, 0);
        }
        __syncthreads();
    }
#pragma unroll
    for (int mi = 0; mi < 2; mi++)
#pragma unroll
        for (int ni = 0; ni < 2; ni++)
#pragma unroll
            for (int r = 0; r < 4; r++) {
                int row = wr * 32 + mi * 16 + (lane >> 4) * 4 + r;
                if (mb + row < n) {
                    int pid = rowpid[row];
                    int col = nb + wc * 32 + ni * 16 + (lane & 15);
                    float v1 = acc1[mi][ni][r], v3 = acc3[mi][ni][r];
                    float sil = v1 / (1.f + expf(-v1));
                    g[(size_t)pid * HC + col] = f2bf(sil * v3);
                }
            }
}

// ---- MoE down, MFMA bf16: yp[pid][:] (+)= g[pid] @ w2[e][c0:c0+HC, :]
__global__ __launch_bounds__(256) void moe_down_mfma(
    const short* __restrict__ g, const float* __restrict__ w2,
    const int* __restrict__ list, const int* __restrict__ counts,
    float* __restrict__ yp, int c0, int first) {
    int e = blockIdx.z;
    int n = counts[e];
    int mb = blockIdx.y * 64;
    if (mb >= n) return;
    int nb = blockIdx.x * 64;
    const float* Bg = w2 + (size_t)e * HID * D + (size_t)c0 * D + nb;
    __shared__ short As[64 * 64];  // [m][k] swizzled (bf16 source)
    __shared__ short Bs[64 * 64];  // [n][k] swizzled (transposed)
    __shared__ int rowpid[64];
    int tid = threadIdx.x;
    int lane = tid & 63, wave = tid >> 6;
    int wr = wave >> 1, wc = wave & 1;
    if (tid < 64) {
        int r = mb + tid;
        rowpid[tid] = (r < n) ? list[e * T + r] : list[e * T];
    }
    __syncthreads();

    f32x4 acc[2][2] = {};

    for (int k0 = 0; k0 < HC; k0 += 64) {
        // stage A: bf16 rows gathered by pid (16B copies)
#pragma unroll
        for (int i = 0; i < 2; i++) {
            int idx = tid + i * 256;
            int r = idx >> 3, kq = (idx & 7) * 8;
            const short* src = g + (size_t)rowpid[r] * HC + k0 + kq;
            bf16x8 v = *(const bf16x8*)src;
            *(bf16x8*)&As[swz(r, kq)] = v;
        }
        // stage B transposed: w2 [k][n] fp32 -> [n][k] bf16
#pragma unroll
        for (int i = 0; i < 4; i++) {
            int idx = tid + i * 256;
            int kr = idx >> 4, n0 = (idx & 15) * 4;
            float4 v = *(const float4*)(Bg + (size_t)(k0 + kr) * D + n0);
            Bs[swz(n0 + 0, kr)] = f2bf(v.x); Bs[swz(n0 + 1, kr)] = f2bf(v.y);
            Bs[swz(n0 + 2, kr)] = f2bf(v.z); Bs[swz(n0 + 3, kr)] = f2bf(v.w);
        }
        __syncthreads();
#pragma unroll
        for (int kk = 0; kk < 64; kk += 32) {
            int krd = kk + 8 * (lane >> 4);
            bf16x8 a0 = *(const bf16x8*)&As[swz(wr * 32 + (lane & 15), krd)];
            bf16x8 a1 = *(const bf16x8*)&As[swz(wr * 32 + 16 + (lane & 15), krd)];
            bf16x8 b0 = *(const bf16x8*)&Bs[swz(wc * 32 + (lane & 15), krd)];
            bf16x8 b1 = *(const bf16x8*)&Bs[swz(wc * 32 + 16 + (lane & 15), krd)];
            acc[0][0] = __builtin_amdgcn_mfma_f32_16x16x32_bf16(a0, b0, acc[0][0], 0, 0, 0);
            acc[0][1] = __builtin_amdgcn_mfma_f32_16x16x32_bf16(a0, b1, acc[0][1], 0, 0, 0);
            acc[1][0] = __builtin_amdgcn_mfma_f32_16x16x32_bf16(a1, b0, acc[1][0], 0, 0, 0);
            acc[1][1] = __builtin_amdgcn_mfma_f32_16x16x32_bf16(a1, b1, acc[1][1], 0, 0, 0);
        }
        __syncthreads();
    }
#pragma unroll
    for (int mi = 0; mi < 2; mi++)
#pragma unroll
        for (int ni = 0; ni < 2; ni++)
#pragma unroll
            for (int r = 0; r < 4; r++) {
                int row = wr * 32 + mi * 16 + (lane >> 4) * 4 + r;
                if (mb + row < n) {
                    int pid = rowpid[row];
                    int col = nb + wc * 32 + ni * 16 + (lane & 15);
                    size_t o = (size_t)pid * D + col;
                    yp[o] = first ? acc[mi][ni][r] : (yp[o] + acc[mi][ni][r]);
                }
            }
}

// ---------------- final combine ----------------
__global__ void combine_kernel(const float* __restrict__ yp, const float* __restrict__ wtok,
                               float* __restrict__ out) {
    int idx = blockIdx.x * 256 + threadIdx.x; // T * (D/4)
    if (idx >= T * (D / 4)) return;
    int t = idx / (D / 4);
    int d4 = idx % (D / 4);
    float4 a = ((const float4*)(out + (size_t)t * D))[d4];
    float4 y0 = ((const float4*)(yp + (size_t)(2 * t) * D))[d4];
    float4 y1 = ((const float4*)(yp + (size_t)(2 * t + 1) * D))[d4];
    float w0 = wtok[2 * t], w1 = wtok[2 * t + 1];
    a.x += w0 * y0.x + w1 * y1.x;
    a.y += w0 * y0.y + w1 * y1.y;
    a.z += w0 * y0.z + w1 * y1.z;
    a.w += w0 * y0.w + w1 * y1.w;
    ((float4*)(out + (size_t)t * D))[d4] = a;
}

extern "C" void kernel_launch(void* const* d_in, const int* in_sizes, int n_in,
                              void* d_out, int out_size, void* d_ws, size_t ws_size,
                              hipStream_t stream) {
    const float* x    = (const float*)d_in[0];
    const float* n1w  = (const float*)d_in[1];
    const float* n2w  = (const float*)d_in[2];
    const float* wq   = (const float*)d_in[3];
    const float* wdkv = (const float*)d_in[4];
    const float* wuk  = (const float*)d_in[5];
    const float* wuv  = (const float*)d_in[6];
    const float* wo   = (const float*)d_in[7];
    const float* gw   = (const float*)d_in[8];
    const float* w1   = (const float*)d_in[9];
    const float* w2   = (const float*)d_in[10];
    const float* w3   = (const float*)d_in[11];
    const int*   sp   = (const int*)d_in[12];
    float* out = (float*)d_out;

    // ws layout (floats). Total ~15.0 MB.
    float* ws = (float*)d_ws;
    float* A_  = ws + 0;                 // 786432: qb, later h2b
    float* B_  = ws + 786432;            // 786432: kb, later yp[0..]
    float* C_  = ws + 1572864;           // 786432: vb, later yp[..]
    float* Dd  = ws + 2359296;           // 786432: h, later ab
    float* cb  = ws + 3145728;           // 65536
    float* probs = ws + 3211264;         // 8192
    float* wtok  = ws + 3219456;         // 2048
    int*   list  = (int*)(ws + 3221504); // 8192 ints
    int*   counts= (int*)(ws + 3229696); // 16 ints
    short* gch   = (short*)(ws + 3229712); // 2T*HC bf16 = 2 MB
    float* yp = B_;                      // 2T*D fp32 (B_ and C_ contiguous)

    hipMemsetAsync(counts, 0, 16 * sizeof(int), stream);

    // ---- attention ----
    rmsnorm_kernel<<<T, 256, 0, stream>>>(x, n1w, Dd);                                   // h
    gemm64<false><<<dim3(D / 64, T / 64), 256, 0, stream>>>(Dd, wq, nullptr, A_, T, D, D);   // qb
    gemm64<false><<<dim3(1, T / 64), 256, 0, stream>>>(Dd, wdkv, nullptr, cb, T, DL, D);     // c
    gemm64<false><<<dim3(D / 64, T / 64), 256, 0, stream>>>(cb, wuk, nullptr, B_, T, D, DL); // kb
    gemm64<false><<<dim3(D / 64, T / 64), 256, 0, stream>>>(cb, wuv, nullptr, C_, T, D, DL); // vb
    rope_kernel<<<(T * H * 32 + 255) / 256, 256, 0, stream>>>(A_, B_, sp);
    attn_kernel<<<BATCH * H * SEQ, 64, 0, stream>>>(A_, B_, C_, Dd);                     // ab
    gemm64<true><<<dim3(D / 64, T / 64), 256, 0, stream>>>(Dd, wo, x, out, T, D, D);     // x1 in out

    // ---- MoE ----
    rmsnorm_kernel<<<T, 256, 0, stream>>>(out, n2w, A_);                                 // h2
    routing_kernel<<<T, 64, 0, stream>>>(A_, gw, probs, list, counts, wtok);
    aux_kernel<<<1, 256, 0, stream>>>(probs, counts, out + (out_size - 1));
    for (int c0 = 0; c0 < HID; c0 += HC) {
        moe_up_mfma<<<dim3(HC / 64, T / 64, E), 256, 0, stream>>>(A_, w1, w3, list, counts, gch, c0);
        moe_down_mfma<<<dim3(D / 64, T / 64, E), 256, 0, stream>>>(gch, w2, list, counts, yp, c0, c0 == 0 ? 1 : 0);
    }
    combine_kernel<<<(T * (D / 4) + 255) / 256, 256, 0, stream>>>(yp, wtok, out);
}

// Round 6
// 655.489 us; speedup vs baseline: 2.2422x; 1.1882x over previous
//
#include <hip/hip_runtime.h>
#include <math.h>

#define T 1024
#define SEQ 512
#define BATCH 2
#define D 768
#define H 12
#define DH 64
#define DL 64
#define E 8
#define HID 3072
#define HC 512   // HID chunk for MoE g materialization

typedef __attribute__((ext_vector_type(8))) short bf16x8;
typedef __attribute__((ext_vector_type(4))) float f32x4;

// fp32 -> bf16 round-to-nearest-even
__device__ inline short f2bf(float f) {
    unsigned u = __float_as_uint(f);
    unsigned r = u + 0x7fff + ((u >> 16) & 1);
    return (short)(r >> 16);
}

// swizzled LDS index (shorts): tile stored [row][k], 64 k per row.
__device__ inline int swz(int row, int k) { return (row * 64 + k) ^ ((row & 7) << 3); }

// ---------------- rmsnorm ----------------
__global__ void rmsnorm_kernel(const float* __restrict__ x, const float* __restrict__ w,
                               float* __restrict__ out) {
    int t = blockIdx.x;
    int tid = threadIdx.x; // 256
    const float* xr = x + (size_t)t * D;
    float s = 0.f;
    for (int i = tid; i < D; i += 256) { float v = xr[i]; s += v * v; }
    __shared__ float red[256];
    red[tid] = s; __syncthreads();
    for (int o = 128; o > 0; o >>= 1) { if (tid < o) red[tid] += red[tid + o]; __syncthreads(); }
    float scale = 1.0f / sqrtf(red[0] / (float)D + 1e-6f);
    for (int i = tid; i < D; i += 256) out[(size_t)t * D + i] = xr[i] * scale * w[i];
}

// ---------------- generic fp32 GEMM (attention-side, unchanged) ----------------
template<bool RES>
__global__ void gemm64(const float* __restrict__ A, const float* __restrict__ B,
                       const float* __restrict__ Rp, float* __restrict__ C,
                       int M, int N, int K) {
    __shared__ float As[16][65];
    __shared__ float Bs[16][68];
    int tid = threadIdx.x;
    int mb = blockIdx.y * 64, nb = blockIdx.x * 64;
    int tr = tid >> 4, tc = tid & 15;
    int aRow = tid >> 2, aCol = (tid & 3) * 4;
    int bRow = tid >> 4, bCol = (tid & 15) * 4;
    float acc[4][4] = {};
    for (int k0 = 0; k0 < K; k0 += 16) {
        float4 av = make_float4(0.f, 0.f, 0.f, 0.f);
        int ar = mb + aRow;
        if (ar < M) av = *(const float4*)(A + (size_t)ar * K + k0 + aCol);
        As[aCol + 0][aRow] = av.x; As[aCol + 1][aRow] = av.y;
        As[aCol + 2][aRow] = av.z; As[aCol + 3][aRow] = av.w;
        float4 bv = make_float4(0.f, 0.f, 0.f, 0.f);
        int bc = nb + bCol;
        if (bc < N) bv = *(const float4*)(B + (size_t)(k0 + bRow) * N + bc);
        *(float4*)&Bs[bRow][bCol] = bv;
        __syncthreads();
#pragma unroll
        for (int kk = 0; kk < 16; kk++) {
            float a[4], b[4];
#pragma unroll
            for (int i = 0; i < 4; i++) a[i] = As[kk][tr * 4 + i];
#pragma unroll
            for (int j = 0; j < 4; j++) b[j] = Bs[kk][tc * 4 + j];
#pragma unroll
            for (int i = 0; i < 4; i++)
#pragma unroll
                for (int j = 0; j < 4; j++) acc[i][j] += a[i] * b[j];
        }
        __syncthreads();
    }
#pragma unroll
    for (int i = 0; i < 4; i++) {
        int r = mb + tr * 4 + i;
        if (r >= M) continue;
#pragma unroll
        for (int j = 0; j < 4; j++) {
            int cn = nb + tc * 4 + j;
            if (cn >= N) continue;
            float val = acc[i][j];
            if (RES) val += Rp[(size_t)r * N + cn];
            C[(size_t)r * N + cn] = val;
        }
    }
}

// ---------------- RoPE (in-place on q and k) ----------------
__global__ void rope_kernel(float* __restrict__ qb, float* __restrict__ kb,
                            const int* __restrict__ spp) {
    int p = blockIdx.x * 256 + threadIdx.x; // T*H*32
    if (p >= T * H * 32) return;
    int i = p & 31;
    int rem = p >> 5;
    int h = rem % H;
    int ts = rem / H;
    int s = ts % SEQ;
    float invf = powf(10000.0f, -(float)(2 * i) / 64.0f);
    float ang = (float)(s + spp[0]) * invf;
    float c = cosf(ang), sn = sinf(ang);
    size_t base = (size_t)ts * D + h * DH;
    float x1 = qb[base + i], x2 = qb[base + 32 + i];
    qb[base + i] = x1 * c - x2 * sn;
    qb[base + 32 + i] = x1 * sn + x2 * c;
    x1 = kb[base + i]; x2 = kb[base + 32 + i];
    kb[base + i] = x1 * c - x2 * sn;
    kb[base + 32 + i] = x1 * sn + x2 * c;
}

// ---------------- flash attention, MFMA bf16 ----------------
// grid (8, H, BATCH); block 256 (4 waves). Wave w owns q-rows [qt*64 + w*16, +16).
__global__ __launch_bounds__(256) void attn_mfma(
    const float* __restrict__ q, const float* __restrict__ k,
    const float* __restrict__ v, float* __restrict__ a) {
    int qt = blockIdx.x, h = blockIdx.y, b = blockIdx.z;
    int tid = threadIdx.x, lane = tid & 63, wave = tid >> 6;
    __shared__ short Qs[64 * 64];  // [q][d] swz
    __shared__ short Ks[64 * 64];  // [kv][d] swz
    __shared__ short Vs[64 * 64];  // [d][kv] swz (transposed)
    __shared__ short Ps[64 * 64];  // [q][kv] swz
    int qbase = qt * 64;

    // stage Q (rows qbase..+63)
    {
        int r = tid >> 2, d0 = (tid & 3) * 16;
        const float* src = q + ((size_t)(b * SEQ + qbase + r)) * D + h * DH + d0;
#pragma unroll
        for (int j = 0; j < 4; j++) {
            float4 vv = *(const float4*)(src + j * 4);
            *(short4*)&Qs[swz(r, d0 + j * 4)] =
                make_short4(f2bf(vv.x), f2bf(vv.y), f2bf(vv.z), f2bf(vv.w));
        }
    }
    __syncthreads();
    // Q fragments for this wave (row = lane&15 within 16-row subtile, k = d)
    bf16x8 qf0 = *(const bf16x8*)&Qs[swz(wave * 16 + (lane & 15), 8 * (lane >> 4))];
    bf16x8 qf1 = *(const bf16x8*)&Qs[swz(wave * 16 + (lane & 15), 32 + 8 * (lane >> 4))];

    float m_run[4] = {-1e30f, -1e30f, -1e30f, -1e30f};
    float l_run[4] = {0.f, 0.f, 0.f, 0.f};
    f32x4 o[4] = {};

    for (int kt = 0; kt <= qt; kt++) {
        int kvbase = kt * 64;
        // stage K [kv][d]
        {
            int r = tid >> 2, d0 = (tid & 3) * 16;
            const float* src = k + ((size_t)(b * SEQ + kvbase + r)) * D + h * DH + d0;
#pragma unroll
            for (int j = 0; j < 4; j++) {
                float4 vv = *(const float4*)(src + j * 4);
                *(short4*)&Ks[swz(r, d0 + j * 4)] =
                    make_short4(f2bf(vv.x), f2bf(vv.y), f2bf(vv.z), f2bf(vv.w));
            }
        }
        // stage V transposed -> [d][kv]
#pragma unroll
        for (int i = 0; i < 4; i++) {
            int idx = tid + i * 256;
            int kr = idx >> 4, d0 = (idx & 15) * 4;
            float4 vv = *(const float4*)(v + ((size_t)(b * SEQ + kvbase + kr)) * D + h * DH + d0);
            Vs[swz(d0 + 0, kr)] = f2bf(vv.x); Vs[swz(d0 + 1, kr)] = f2bf(vv.y);
            Vs[swz(d0 + 2, kr)] = f2bf(vv.z); Vs[swz(d0 + 3, kr)] = f2bf(vv.w);
        }
        __syncthreads();

        // S = Q @ K^T for 4 kv-subtiles (each 16 kv)
        f32x4 s[4];
#pragma unroll
        for (int kvt = 0; kvt < 4; kvt++) {
            bf16x8 kf0 = *(const bf16x8*)&Ks[swz(kvt * 16 + (lane & 15), 8 * (lane >> 4))];
            bf16x8 kf1 = *(const bf16x8*)&Ks[swz(kvt * 16 + (lane & 15), 32 + 8 * (lane >> 4))];
            f32x4 z = {};
            z = __builtin_amdgcn_mfma_f32_16x16x32_bf16(qf0, kf0, z, 0, 0, 0);
            z = __builtin_amdgcn_mfma_f32_16x16x32_bf16(qf1, kf1, z, 0, 0, 0);
            s[kvt] = z;
        }
        // scale + causal mask (diagonal tile only)
#pragma unroll
        for (int kvt = 0; kvt < 4; kvt++) {
#pragma unroll
            for (int r = 0; r < 4; r++) {
                float val = s[kvt][r] * 0.125f;
                if (kt == qt) {
                    int kv_abs = kvbase + kvt * 16 + (lane & 15);
                    int q_abs = qbase + wave * 16 + (lane >> 4) * 4 + r;
                    if (kv_abs > q_abs) val = -1e30f;
                }
                s[kvt][r] = val;
            }
        }
        // online softmax stats (4 q-rows per lane, reduce over 16 lanes)
        float mnew[4], psum[4], scl[4];
#pragma unroll
        for (int r = 0; r < 4; r++) {
            float mx = fmaxf(fmaxf(s[0][r], s[1][r]), fmaxf(s[2][r], s[3][r]));
#pragma unroll
            for (int o2 = 8; o2 > 0; o2 >>= 1) mx = fmaxf(mx, __shfl_xor(mx, o2));
            mnew[r] = fmaxf(m_run[r], mx);
            float ps = 0.f;
#pragma unroll
            for (int kvt = 0; kvt < 4; kvt++) {
                float p = expf(s[kvt][r] - mnew[r]);
                s[kvt][r] = p;
                ps += p;
            }
#pragma unroll
            for (int o2 = 8; o2 > 0; o2 >>= 1) ps += __shfl_xor(ps, o2);
            psum[r] = ps;
            scl[r] = expf(m_run[r] - mnew[r]);
            m_run[r] = mnew[r];
            l_run[r] = l_run[r] * scl[r] + psum[r];
        }
        // rescale O
#pragma unroll
        for (int dt = 0; dt < 4; dt++)
#pragma unroll
            for (int r = 0; r < 4; r++) o[dt][r] *= scl[r];
        // write P (bf16) to LDS [q][kv]
#pragma unroll
        for (int kvt = 0; kvt < 4; kvt++)
#pragma unroll
            for (int r = 0; r < 4; r++)
                Ps[swz(wave * 16 + (lane >> 4) * 4 + r, kvt * 16 + (lane & 15))] = f2bf(s[kvt][r]);
        __syncthreads();
        // O += P @ V
        bf16x8 pa0 = *(const bf16x8*)&Ps[swz(wave * 16 + (lane & 15), 8 * (lane >> 4))];
        bf16x8 pa1 = *(const bf16x8*)&Ps[swz(wave * 16 + (lane & 15), 32 + 8 * (lane >> 4))];
#pragma unroll
        for (int dt = 0; dt < 4; dt++) {
            bf16x8 vf0 = *(const bf16x8*)&Vs[swz(dt * 16 + (lane & 15), 8 * (lane >> 4))];
            bf16x8 vf1 = *(const bf16x8*)&Vs[swz(dt * 16 + (lane & 15), 32 + 8 * (lane >> 4))];
            o[dt] = __builtin_amdgcn_mfma_f32_16x16x32_bf16(pa0, vf0, o[dt], 0, 0, 0);
            o[dt] = __builtin_amdgcn_mfma_f32_16x16x32_bf16(pa1, vf1, o[dt], 0, 0, 0);
        }
        __syncthreads();
    }
    // normalize + store
#pragma unroll
    for (int r = 0; r < 4; r++) {
        float inv = 1.0f / l_run[r];
        int qrow = qbase + wave * 16 + (lane >> 4) * 4 + r;
#pragma unroll
        for (int dt = 0; dt < 4; dt++) {
            a[((size_t)(b * SEQ + qrow)) * D + h * DH + dt * 16 + (lane & 15)] = o[dt][r] * inv;
        }
    }
}

// ---------------- routing ----------------
__global__ void routing_kernel(const float* __restrict__ h2, const float* __restrict__ gw,
                               float* __restrict__ probs, int* __restrict__ list,
                               int* __restrict__ counts, float* __restrict__ wtok) {
    int t = blockIdx.x;
    int tid = threadIdx.x; // 64
    __shared__ float part[64][8];
    float l[8] = {0.f, 0.f, 0.f, 0.f, 0.f, 0.f, 0.f, 0.f};
    const float* hr = h2 + (size_t)t * D;
    for (int i = tid; i < D; i += 64) {
        float hv = hr[i];
        const float* g = gw + (size_t)i * E;
#pragma unroll
        for (int e = 0; e < 8; e++) l[e] += hv * g[e];
    }
#pragma unroll
    for (int e = 0; e < 8; e++) part[tid][e] = l[e];
    __syncthreads();
    if (tid == 0) {
        float lg[8];
#pragma unroll
        for (int e = 0; e < 8; e++) {
            float s = 0.f;
            for (int j = 0; j < 64; j++) s += part[j][e];
            lg[e] = s;
        }
        float m = lg[0];
#pragma unroll
        for (int e = 1; e < 8; e++) m = fmaxf(m, lg[e]);
        float se = 0.f;
        float pr[8];
#pragma unroll
        for (int e = 0; e < 8; e++) { pr[e] = expf(lg[e] - m); se += pr[e]; }
#pragma unroll
        for (int e = 0; e < 8; e++) { pr[e] /= se; probs[t * 8 + e] = pr[e]; }
        int i0 = 0;
#pragma unroll
        for (int e = 1; e < 8; e++) if (pr[e] > pr[i0]) i0 = e;
        int i1 = -1;
#pragma unroll
        for (int e = 0; e < 8; e++) {
            if (e == i0) continue;
            if (i1 < 0 || pr[e] > pr[i1]) i1 = e;
        }
        float w0 = pr[i0], w1 = pr[i1];
        float wsum = w0 + w1;
        wtok[t * 2 + 0] = w0 / wsum;
        wtok[t * 2 + 1] = w1 / wsum;
        int p0 = atomicAdd(&counts[i0], 1); list[i0 * T + p0] = t * 2 + 0;
        int p1 = atomicAdd(&counts[i1], 1); list[i1 * T + p1] = t * 2 + 1;
    }
}

// ---------------- aux loss ----------------
__global__ void aux_kernel(const float* __restrict__ probs, const int* __restrict__ counts,
                           float* __restrict__ out_aux) {
    int tid = threadIdx.x;
    __shared__ float ps[8];
    if (tid < 8) {
        float s = 0.f;
        for (int t = 0; t < T; t++) s += probs[t * 8 + tid];
        ps[tid] = s;
    }
    __syncthreads();
    if (tid == 0) {
        float aux = 0.f;
        for (int e = 0; e < 8; e++) {
            float f = (float)counts[e] / (float)T;
            float P = ps[e] / (float)T;
            aux += f * P;
        }
        out_aux[0] = (float)E * aux;
    }
}

// ---- MoE up, MFMA bf16 ----
__global__ __launch_bounds__(256) void moe_up_mfma(
    const float* __restrict__ h2, const float* __restrict__ w1, const float* __restrict__ w3,
    const int* __restrict__ list, const int* __restrict__ counts,
    short* __restrict__ g, int c0) {
    int e = blockIdx.z;
    int n = counts[e];
    int mb = blockIdx.y * 64;
    if (mb >= n) return;
    int nb = blockIdx.x * 64;  // col within chunk
    const float* B1g = w1 + (size_t)e * D * HID + (c0 + nb);
    const float* B3g = w3 + (size_t)e * D * HID + (c0 + nb);
    __shared__ short As[64 * 64];   // [m][k] swizzled
    __shared__ short B1s[64 * 64];  // [n][k] swizzled (transposed)
    __shared__ short B3s[64 * 64];
    __shared__ int rowpid[64];
    __shared__ int rowtok[64];
    int tid = threadIdx.x;
    int lane = tid & 63, wave = tid >> 6;
    int wr = wave >> 1, wc = wave & 1;
    if (tid < 64) {
        int r = mb + tid;
        int pid = (r < n) ? list[e * T + r] : list[e * T];
        rowpid[tid] = pid;
        rowtok[tid] = pid >> 1;
    }
    __syncthreads();

    f32x4 acc1[2][2] = {};
    f32x4 acc3[2][2] = {};
    int ar = tid >> 2, ac = (tid & 3) * 16;
    const float* Arow = h2 + (size_t)rowtok[ar] * D + ac;

    for (int k0 = 0; k0 < D; k0 += 64) {
#pragma unroll
        for (int j = 0; j < 4; j++) {
            float4 v = *(const float4*)(Arow + k0 + j * 4);
            short4 s4 = make_short4(f2bf(v.x), f2bf(v.y), f2bf(v.z), f2bf(v.w));
            *(short4*)&As[swz(ar, ac + j * 4)] = s4;
        }
#pragma unroll
        for (int i = 0; i < 4; i++) {
            int idx = tid + i * 256;
            int kr = idx >> 4, n0 = (idx & 15) * 4;
            float4 v1 = *(const float4*)(B1g + (size_t)(k0 + kr) * HID + n0);
            float4 v3 = *(const float4*)(B3g + (size_t)(k0 + kr) * HID + n0);
            B1s[swz(n0 + 0, kr)] = f2bf(v1.x); B1s[swz(n0 + 1, kr)] = f2bf(v1.y);
            B1s[swz(n0 + 2, kr)] = f2bf(v1.z); B1s[swz(n0 + 3, kr)] = f2bf(v1.w);
            B3s[swz(n0 + 0, kr)] = f2bf(v3.x); B3s[swz(n0 + 1, kr)] = f2bf(v3.y);
            B3s[swz(n0 + 2, kr)] = f2bf(v3.z); B3s[swz(n0 + 3, kr)] = f2bf(v3.w);
        }
        __syncthreads();
#pragma unroll
        for (int kk = 0; kk < 64; kk += 32) {
            int krd = kk + 8 * (lane >> 4);
            bf16x8 a0  = *(const bf16x8*)&As[swz(wr * 32 + (lane & 15), krd)];
            bf16x8 a1  = *(const bf16x8*)&As[swz(wr * 32 + 16 + (lane & 15), krd)];
            bf16x8 b10 = *(const bf16x8*)&B1s[swz(wc * 32 + (lane & 15), krd)];
            bf16x8 b11 = *(const bf16x8*)&B1s[swz(wc * 32 + 16 + (lane & 15), krd)];
            bf16x8 b30 = *(const bf16x8*)&B3s[swz(wc * 32 + (lane & 15), krd)];
            bf16x8 b31 = *(const bf16x8*)&B3s[swz(wc * 32 + 16 + (lane & 15), krd)];
            acc1[0][0] = __builtin_amdgcn_mfma_f32_16x16x32_bf16(a0, b10, acc1[0][0], 0, 0, 0);
            acc1[0][1] = __builtin_amdgcn_mfma_f32_16x16x32_bf16(a0, b11, acc1[0][1], 0, 0, 0);
            acc1[1][0] = __builtin_amdgcn_mfma_f32_16x16x32_bf16(a1, b10, acc1[1][0], 0, 0, 0);
            acc1[1][1] = __builtin_amdgcn_mfma_f32_16x16x32_bf16(a1, b11, acc1[1][1], 0, 0, 0);
            acc3[0][0] = __builtin_amdgcn_mfma_f32_16x16x32_bf16(a0, b30, acc3[0][0], 0, 0, 0);
            acc3[0][1] = __builtin_amdgcn_mfma_f32_16x16x32_bf16(a0, b31, acc3[0][1], 0, 0, 0);
            acc3[1][0] = __builtin_amdgcn_mfma_f32_16x16x32_bf16(a1, b30, acc3[1][0], 0, 0, 0);
            acc3[1][1] = __builtin_amdgcn_mfma_f32_16x16x32_bf16(a1, b31, acc3[1][1], 0, 0, 0);
        }
        __syncthreads();
    }
#pragma unroll
    for (int mi = 0; mi < 2; mi++)
#pragma unroll
        for (int ni = 0; ni < 2; ni++)
#pragma unroll
            for (int r = 0; r < 4; r++) {
                int row = wr * 32 + mi * 16 + (lane >> 4) * 4 + r;
                if (mb + row < n) {
                    int pid = rowpid[row];
                    int col = nb + wc * 32 + ni * 16 + (lane & 15);
                    float v1 = acc1[mi][ni][r], v3 = acc3[mi][ni][r];
                    float sil = v1 / (1.f + expf(-v1));
                    g[(size_t)pid * HC + col] = f2bf(sil * v3);
                }
            }
}

// ---- MoE down, MFMA bf16 ----
__global__ __launch_bounds__(256) void moe_down_mfma(
    const short* __restrict__ g, const float* __restrict__ w2,
    const int* __restrict__ list, const int* __restrict__ counts,
    float* __restrict__ yp, int c0, int first) {
    int e = blockIdx.z;
    int n = counts[e];
    int mb = blockIdx.y * 64;
    if (mb >= n) return;
    int nb = blockIdx.x * 64;
    const float* Bg = w2 + (size_t)e * HID * D + (size_t)c0 * D + nb;
    __shared__ short As[64 * 64];
    __shared__ short Bs[64 * 64];
    __shared__ int rowpid[64];
    int tid = threadIdx.x;
    int lane = tid & 63, wave = tid >> 6;
    int wr = wave >> 1, wc = wave & 1;
    if (tid < 64) {
        int r = mb + tid;
        rowpid[tid] = (r < n) ? list[e * T + r] : list[e * T];
    }
    __syncthreads();

    f32x4 acc[2][2] = {};

    for (int k0 = 0; k0 < HC; k0 += 64) {
#pragma unroll
        for (int i = 0; i < 2; i++) {
            int idx = tid + i * 256;
            int r = idx >> 3, kq = (idx & 7) * 8;
            const short* src = g + (size_t)rowpid[r] * HC + k0 + kq;
            bf16x8 v = *(const bf16x8*)src;
            *(bf16x8*)&As[swz(r, kq)] = v;
        }
#pragma unroll
        for (int i = 0; i < 4; i++) {
            int idx = tid + i * 256;
            int kr = idx >> 4, n0 = (idx & 15) * 4;
            float4 v = *(const float4*)(Bg + (size_t)(k0 + kr) * D + n0);
            Bs[swz(n0 + 0, kr)] = f2bf(v.x); Bs[swz(n0 + 1, kr)] = f2bf(v.y);
            Bs[swz(n0 + 2, kr)] = f2bf(v.z); Bs[swz(n0 + 3, kr)] = f2bf(v.w);
        }
        __syncthreads();
#pragma unroll
        for (int kk = 0; kk < 64; kk += 32) {
            int krd = kk + 8 * (lane >> 4);
            bf16x8 a0 = *(const bf16x8*)&As[swz(wr * 32 + (lane & 15), krd)];
            bf16x8 a1 = *(const bf16x8*)&As[swz(wr * 32 + 16 + (lane & 15), krd)];
            bf16x8 b0 = *(const bf16x8*)&Bs[swz(wc * 32 + (lane & 15), krd)];
            bf16x8 b1 = *(const bf16x8*)&Bs[swz(wc * 32 + 16 + (lane & 15), krd)];
            acc[0][0] = __builtin_amdgcn_mfma_f32_16x16x32_bf16(a0, b0, acc[0][0], 0, 0, 0);
            acc[0][1] = __builtin_amdgcn_mfma_f32_16x16x32_bf16(a0, b1, acc[0][1], 0, 0, 0);
            acc[1][0] = __builtin_amdgcn_mfma_f32_16x16x32_bf16(a1, b0, acc[1][0], 0, 0, 0);
            acc[1][1] = __builtin_amdgcn_mfma_f32_16x16x32_bf16(a1, b1, acc[1][1], 0, 0, 0);
        }
        __syncthreads();
    }
#pragma unroll
    for (int mi = 0; mi < 2; mi++)
#pragma unroll
        for (int ni = 0; ni < 2; ni++)
#pragma unroll
            for (int r = 0; r < 4; r++) {
                int row = wr * 32 + mi * 16 + (lane >> 4) * 4 + r;
                if (mb + row < n) {
                    int pid = rowpid[row];
                    int col = nb + wc * 32 + ni * 16 + (lane & 15);
                    size_t o = (size_t)pid * D + col;
                    yp[o] = first ? acc[mi][ni][r] : (yp[o] + acc[mi][ni][r]);
                }
            }
}

// ---------------- final combine ----------------
__global__ void combine_kernel(const float* __restrict__ yp, const float* __restrict__ wtok,
                               float* __restrict__ out) {
    int idx = blockIdx.x * 256 + threadIdx.x; // T * (D/4)
    if (idx >= T * (D / 4)) return;
    int t = idx / (D / 4);
    int d4 = idx % (D / 4);
    float4 a = ((const float4*)(out + (size_t)t * D))[d4];
    float4 y0 = ((const float4*)(yp + (size_t)(2 * t) * D))[d4];
    float4 y1 = ((const float4*)(yp + (size_t)(2 * t + 1) * D))[d4];
    float w0 = wtok[2 * t], w1 = wtok[2 * t + 1];
    a.x += w0 * y0.x + w1 * y1.x;
    a.y += w0 * y0.y + w1 * y1.y;
    a.z += w0 * y0.z + w1 * y1.z;
    a.w += w0 * y0.w + w1 * y1.w;
    ((float4*)(out + (size_t)t * D))[d4] = a;
}

extern "C" void kernel_launch(void* const* d_in, const int* in_sizes, int n_in,
                              void* d_out, int out_size, void* d_ws, size_t ws_size,
                              hipStream_t stream) {
    const float* x    = (const float*)d_in[0];
    const float* n1w  = (const float*)d_in[1];
    const float* n2w  = (const float*)d_in[2];
    const float* wq   = (const float*)d_in[3];
    const float* wdkv = (const float*)d_in[4];
    const float* wuk  = (const float*)d_in[5];
    const float* wuv  = (const float*)d_in[6];
    const float* wo   = (const float*)d_in[7];
    const float* gw   = (const float*)d_in[8];
    const float* w1   = (const float*)d_in[9];
    const float* w2   = (const float*)d_in[10];
    const float* w3   = (const float*)d_in[11];
    const int*   sp   = (const int*)d_in[12];
    float* out = (float*)d_out;

    // ws layout (floats). Total ~15.0 MB.
    float* ws = (float*)d_ws;
    float* A_  = ws + 0;                 // 786432: qb, later h2b
    float* B_  = ws + 786432;            // 786432: kb, later yp[0..]
    float* C_  = ws + 1572864;           // 786432: vb, later yp[..]
    float* Dd  = ws + 2359296;           // 786432: h, later ab
    float* cb  = ws + 3145728;           // 65536
    float* probs = ws + 3211264;         // 8192
    float* wtok  = ws + 3219456;         // 2048
    int*   list  = (int*)(ws + 3221504); // 8192 ints
    int*   counts= (int*)(ws + 3229696); // 16 ints
    short* gch   = (short*)(ws + 3229712); // 2T*HC bf16 = 2 MB
    float* yp = B_;                      // 2T*D fp32 (B_ and C_ contiguous)

    hipMemsetAsync(counts, 0, 16 * sizeof(int), stream);

    // ---- attention ----
    rmsnorm_kernel<<<T, 256, 0, stream>>>(x, n1w, Dd);                                   // h
    gemm64<false><<<dim3(D / 64, T / 64), 256, 0, stream>>>(Dd, wq, nullptr, A_, T, D, D);   // qb
    gemm64<false><<<dim3(1, T / 64), 256, 0, stream>>>(Dd, wdkv, nullptr, cb, T, DL, D);     // c
    gemm64<false><<<dim3(D / 64, T / 64), 256, 0, stream>>>(cb, wuk, nullptr, B_, T, D, DL); // kb
    gemm64<false><<<dim3(D / 64, T / 64), 256, 0, stream>>>(cb, wuv, nullptr, C_, T, D, DL); // vb
    rope_kernel<<<(T * H * 32 + 255) / 256, 256, 0, stream>>>(A_, B_, sp);
    attn_mfma<<<dim3(8, H, BATCH), 256, 0, stream>>>(A_, B_, C_, Dd);                    // ab
    gemm64<true><<<dim3(D / 64, T / 64), 256, 0, stream>>>(Dd, wo, x, out, T, D, D);     // x1 in out

    // ---- MoE ----
    rmsnorm_kernel<<<T, 256, 0, stream>>>(out, n2w, A_);                                 // h2
    routing_kernel<<<T, 64, 0, stream>>>(A_, gw, probs, list, counts, wtok);
    aux_kernel<<<1, 256, 0, stream>>>(probs, counts, out + (out_size - 1));
    for (int c0 = 0; c0 < HID; c0 += HC) {
        moe_up_mfma<<<dim3(HC / 64, T / 64, E), 256, 0, stream>>>(A_, w1, w3, list, counts, gch, c0);
        moe_down_mfma<<<dim3(D / 64, T / 64, E), 256, 0, stream>>>(gch, w2, list, counts, yp, c0, c0 == 0 ? 1 : 0);
    }
    combine_kernel<<<(T * (D / 4) + 255) / 256, 256, 0, stream>>>(yp, wtok, out);
}

// Round 7
// 537.315 us; speedup vs baseline: 2.7353x; 1.2199x over previous
//
#include <hip/hip_runtime.h>
#include <math.h>

#define T 1024
#define SEQ 512
#define BATCH 2
#define D 768
#define H 12
#define DH 64
#define DL 64
#define E 8
#define HID 3072
#define HC 512   // HID chunk for MoE g materialization

typedef __attribute__((ext_vector_type(8))) short bf16x8;
typedef __attribute__((ext_vector_type(4))) float f32x4;

// fp32 -> bf16 round-to-nearest-even
__device__ inline short f2bf(float f) {
    unsigned u = __float_as_uint(f);
    unsigned r = u + 0x7fff + ((u >> 16) & 1);
    return (short)(r >> 16);
}

// swizzled LDS index (shorts): tile stored [row][k], 64 k per row.
__device__ inline int swz(int row, int k) { return (row * 64 + k) ^ ((row & 7) << 3); }

// ---------------- rmsnorm ----------------
__global__ void rmsnorm_kernel(const float* __restrict__ x, const float* __restrict__ w,
                               float* __restrict__ out) {
    int t = blockIdx.x;
    int tid = threadIdx.x; // 256
    const float* xr = x + (size_t)t * D;
    float s = 0.f;
    for (int i = tid; i < D; i += 256) { float v = xr[i]; s += v * v; }
    __shared__ float red[256];
    red[tid] = s; __syncthreads();
    for (int o = 128; o > 0; o >>= 1) { if (tid < o) red[tid] += red[tid + o]; __syncthreads(); }
    float scale = 1.0f / sqrtf(red[0] / (float)D + 1e-6f);
    for (int i = tid; i < D; i += 256) out[(size_t)t * D + i] = xr[i] * scale * w[i];
}

// ---------------- dense bf16 MFMA GEMM: C[M,N] = A[M,K]@B[K,N] (+R). 64|M,N,K ----------------
template<bool RES>
__global__ __launch_bounds__(256) void gemm_bf16(
    const float* __restrict__ A, const float* __restrict__ B,
    const float* __restrict__ Rp, float* __restrict__ C,
    int M, int N, int K) {
    int mb = blockIdx.y * 64, nb = blockIdx.x * 64;
    __shared__ short As[64 * 64];
    __shared__ short Bs[64 * 64];
    int tid = threadIdx.x;
    int lane = tid & 63, wave = tid >> 6;
    int wr = wave >> 1, wc = wave & 1;
    f32x4 acc[2][2] = {};
    int ar = tid >> 2, ac = (tid & 3) * 16;
    const float* Arow = A + (size_t)(mb + ar) * K + ac;
    const float* Bg = B + nb;
    for (int k0 = 0; k0 < K; k0 += 64) {
#pragma unroll
        for (int j = 0; j < 4; j++) {
            float4 v = *(const float4*)(Arow + k0 + j * 4);
            *(short4*)&As[swz(ar, ac + j * 4)] =
                make_short4(f2bf(v.x), f2bf(v.y), f2bf(v.z), f2bf(v.w));
        }
#pragma unroll
        for (int i = 0; i < 4; i++) {
            int idx = tid + i * 256;
            int kr = idx >> 4, n0 = (idx & 15) * 4;
            float4 v = *(const float4*)(Bg + (size_t)(k0 + kr) * N + n0);
            Bs[swz(n0 + 0, kr)] = f2bf(v.x); Bs[swz(n0 + 1, kr)] = f2bf(v.y);
            Bs[swz(n0 + 2, kr)] = f2bf(v.z); Bs[swz(n0 + 3, kr)] = f2bf(v.w);
        }
        __syncthreads();
#pragma unroll
        for (int kk = 0; kk < 64; kk += 32) {
            int krd = kk + 8 * (lane >> 4);
            bf16x8 a0 = *(const bf16x8*)&As[swz(wr * 32 + (lane & 15), krd)];
            bf16x8 a1 = *(const bf16x8*)&As[swz(wr * 32 + 16 + (lane & 15), krd)];
            bf16x8 b0 = *(const bf16x8*)&Bs[swz(wc * 32 + (lane & 15), krd)];
            bf16x8 b1 = *(const bf16x8*)&Bs[swz(wc * 32 + 16 + (lane & 15), krd)];
            acc[0][0] = __builtin_amdgcn_mfma_f32_16x16x32_bf16(a0, b0, acc[0][0], 0, 0, 0);
            acc[0][1] = __builtin_amdgcn_mfma_f32_16x16x32_bf16(a0, b1, acc[0][1], 0, 0, 0);
            acc[1][0] = __builtin_amdgcn_mfma_f32_16x16x32_bf16(a1, b0, acc[1][0], 0, 0, 0);
            acc[1][1] = __builtin_amdgcn_mfma_f32_16x16x32_bf16(a1, b1, acc[1][1], 0, 0, 0);
        }
        __syncthreads();
    }
#pragma unroll
    for (int mi = 0; mi < 2; mi++)
#pragma unroll
        for (int ni = 0; ni < 2; ni++)
#pragma unroll
            for (int r = 0; r < 4; r++) {
                int row = mb + wr * 32 + mi * 16 + (lane >> 4) * 4 + r;
                int col = nb + wc * 32 + ni * 16 + (lane & 15);
                float val = acc[mi][ni][r];
                if (RES) val += Rp[(size_t)row * N + col];
                C[(size_t)row * N + col] = val;
            }
}

// ---- fused K/V up-projection: kb = cb@wuk, vb = cb@wuv (shared A, K=DL=64) ----
__global__ __launch_bounds__(256) void gemm_kuv(
    const float* __restrict__ A, const float* __restrict__ Bk, const float* __restrict__ Bv,
    float* __restrict__ Ck, float* __restrict__ Cv, int M, int N, int K) {
    int mb = blockIdx.y * 64, nb = blockIdx.x * 64;
    __shared__ short As[64 * 64];
    __shared__ short B1s[64 * 64];
    __shared__ short B2s[64 * 64];
    int tid = threadIdx.x;
    int lane = tid & 63, wave = tid >> 6;
    int wr = wave >> 1, wc = wave & 1;
    f32x4 acc1[2][2] = {};
    f32x4 acc2[2][2] = {};
    int ar = tid >> 2, ac = (tid & 3) * 16;
    const float* Arow = A + (size_t)(mb + ar) * K + ac;
    for (int k0 = 0; k0 < K; k0 += 64) {
#pragma unroll
        for (int j = 0; j < 4; j++) {
            float4 v = *(const float4*)(Arow + k0 + j * 4);
            *(short4*)&As[swz(ar, ac + j * 4)] =
                make_short4(f2bf(v.x), f2bf(v.y), f2bf(v.z), f2bf(v.w));
        }
#pragma unroll
        for (int i = 0; i < 4; i++) {
            int idx = tid + i * 256;
            int kr = idx >> 4, n0 = (idx & 15) * 4;
            float4 v1 = *(const float4*)(Bk + (size_t)(k0 + kr) * N + nb + n0);
            float4 v2 = *(const float4*)(Bv + (size_t)(k0 + kr) * N + nb + n0);
            B1s[swz(n0 + 0, kr)] = f2bf(v1.x); B1s[swz(n0 + 1, kr)] = f2bf(v1.y);
            B1s[swz(n0 + 2, kr)] = f2bf(v1.z); B1s[swz(n0 + 3, kr)] = f2bf(v1.w);
            B2s[swz(n0 + 0, kr)] = f2bf(v2.x); B2s[swz(n0 + 1, kr)] = f2bf(v2.y);
            B2s[swz(n0 + 2, kr)] = f2bf(v2.z); B2s[swz(n0 + 3, kr)] = f2bf(v2.w);
        }
        __syncthreads();
#pragma unroll
        for (int kk = 0; kk < 64; kk += 32) {
            int krd = kk + 8 * (lane >> 4);
            bf16x8 a0 = *(const bf16x8*)&As[swz(wr * 32 + (lane & 15), krd)];
            bf16x8 a1 = *(const bf16x8*)&As[swz(wr * 32 + 16 + (lane & 15), krd)];
            bf16x8 p0 = *(const bf16x8*)&B1s[swz(wc * 32 + (lane & 15), krd)];
            bf16x8 p1 = *(const bf16x8*)&B1s[swz(wc * 32 + 16 + (lane & 15), krd)];
            bf16x8 q0 = *(const bf16x8*)&B2s[swz(wc * 32 + (lane & 15), krd)];
            bf16x8 q1 = *(const bf16x8*)&B2s[swz(wc * 32 + 16 + (lane & 15), krd)];
            acc1[0][0] = __builtin_amdgcn_mfma_f32_16x16x32_bf16(a0, p0, acc1[0][0], 0, 0, 0);
            acc1[0][1] = __builtin_amdgcn_mfma_f32_16x16x32_bf16(a0, p1, acc1[0][1], 0, 0, 0);
            acc1[1][0] = __builtin_amdgcn_mfma_f32_16x16x32_bf16(a1, p0, acc1[1][0], 0, 0, 0);
            acc1[1][1] = __builtin_amdgcn_mfma_f32_16x16x32_bf16(a1, p1, acc1[1][1], 0, 0, 0);
            acc2[0][0] = __builtin_amdgcn_mfma_f32_16x16x32_bf16(a0, q0, acc2[0][0], 0, 0, 0);
            acc2[0][1] = __builtin_amdgcn_mfma_f32_16x16x32_bf16(a0, q1, acc2[0][1], 0, 0, 0);
            acc2[1][0] = __builtin_amdgcn_mfma_f32_16x16x32_bf16(a1, q0, acc2[1][0], 0, 0, 0);
            acc2[1][1] = __builtin_amdgcn_mfma_f32_16x16x32_bf16(a1, q1, acc2[1][1], 0, 0, 0);
        }
        __syncthreads();
    }
#pragma unroll
    for (int mi = 0; mi < 2; mi++)
#pragma unroll
        for (int ni = 0; ni < 2; ni++)
#pragma unroll
            for (int r = 0; r < 4; r++) {
                int row = mb + wr * 32 + mi * 16 + (lane >> 4) * 4 + r;
                int col = nb + wc * 32 + ni * 16 + (lane & 15);
                Ck[(size_t)row * N + col] = acc1[mi][ni][r];
                Cv[(size_t)row * N + col] = acc2[mi][ni][r];
            }
}

// ---------------- RoPE (in-place on q and k) ----------------
__global__ void rope_kernel(float* __restrict__ qb, float* __restrict__ kb,
                            const int* __restrict__ spp) {
    int p = blockIdx.x * 256 + threadIdx.x; // T*H*32
    if (p >= T * H * 32) return;
    int i = p & 31;
    int rem = p >> 5;
    int h = rem % H;
    int ts = rem / H;
    int s = ts % SEQ;
    float invf = powf(10000.0f, -(float)(2 * i) / 64.0f);
    float ang = (float)(s + spp[0]) * invf;
    float c = cosf(ang), sn = sinf(ang);
    size_t base = (size_t)ts * D + h * DH;
    float x1 = qb[base + i], x2 = qb[base + 32 + i];
    qb[base + i] = x1 * c - x2 * sn;
    qb[base + 32 + i] = x1 * sn + x2 * c;
    x1 = kb[base + i]; x2 = kb[base + 32 + i];
    kb[base + i] = x1 * c - x2 * sn;
    kb[base + 32 + i] = x1 * sn + x2 * c;
}

// ---------------- flash attention, MFMA bf16 ----------------
__global__ __launch_bounds__(256) void attn_mfma(
    const float* __restrict__ q, const float* __restrict__ k,
    const float* __restrict__ v, float* __restrict__ a) {
    int qt = blockIdx.x, h = blockIdx.y, b = blockIdx.z;
    int tid = threadIdx.x, lane = tid & 63, wave = tid >> 6;
    __shared__ short Qs[64 * 64];
    __shared__ short Ks[64 * 64];
    __shared__ short Vs[64 * 64];
    __shared__ short Ps[64 * 64];
    int qbase = qt * 64;
    {
        int r = tid >> 2, d0 = (tid & 3) * 16;
        const float* src = q + ((size_t)(b * SEQ + qbase + r)) * D + h * DH + d0;
#pragma unroll
        for (int j = 0; j < 4; j++) {
            float4 vv = *(const float4*)(src + j * 4);
            *(short4*)&Qs[swz(r, d0 + j * 4)] =
                make_short4(f2bf(vv.x), f2bf(vv.y), f2bf(vv.z), f2bf(vv.w));
        }
    }
    __syncthreads();
    bf16x8 qf0 = *(const bf16x8*)&Qs[swz(wave * 16 + (lane & 15), 8 * (lane >> 4))];
    bf16x8 qf1 = *(const bf16x8*)&Qs[swz(wave * 16 + (lane & 15), 32 + 8 * (lane >> 4))];

    float m_run[4] = {-1e30f, -1e30f, -1e30f, -1e30f};
    float l_run[4] = {0.f, 0.f, 0.f, 0.f};
    f32x4 o[4] = {};

    for (int kt = 0; kt <= qt; kt++) {
        int kvbase = kt * 64;
        {
            int r = tid >> 2, d0 = (tid & 3) * 16;
            const float* src = k + ((size_t)(b * SEQ + kvbase + r)) * D + h * DH + d0;
#pragma unroll
            for (int j = 0; j < 4; j++) {
                float4 vv = *(const float4*)(src + j * 4);
                *(short4*)&Ks[swz(r, d0 + j * 4)] =
                    make_short4(f2bf(vv.x), f2bf(vv.y), f2bf(vv.z), f2bf(vv.w));
            }
        }
#pragma unroll
        for (int i = 0; i < 4; i++) {
            int idx = tid + i * 256;
            int kr = idx >> 4, d0 = (idx & 15) * 4;
            float4 vv = *(const float4*)(v + ((size_t)(b * SEQ + kvbase + kr)) * D + h * DH + d0);
            Vs[swz(d0 + 0, kr)] = f2bf(vv.x); Vs[swz(d0 + 1, kr)] = f2bf(vv.y);
            Vs[swz(d0 + 2, kr)] = f2bf(vv.z); Vs[swz(d0 + 3, kr)] = f2bf(vv.w);
        }
        __syncthreads();

        f32x4 s[4];
#pragma unroll
        for (int kvt = 0; kvt < 4; kvt++) {
            bf16x8 kf0 = *(const bf16x8*)&Ks[swz(kvt * 16 + (lane & 15), 8 * (lane >> 4))];
            bf16x8 kf1 = *(const bf16x8*)&Ks[swz(kvt * 16 + (lane & 15), 32 + 8 * (lane >> 4))];
            f32x4 z = {};
            z = __builtin_amdgcn_mfma_f32_16x16x32_bf16(qf0, kf0, z, 0, 0, 0);
            z = __builtin_amdgcn_mfma_f32_16x16x32_bf16(qf1, kf1, z, 0, 0, 0);
            s[kvt] = z;
        }
#pragma unroll
        for (int kvt = 0; kvt < 4; kvt++) {
#pragma unroll
            for (int r = 0; r < 4; r++) {
                float val = s[kvt][r] * 0.125f;
                if (kt == qt) {
                    int kv_abs = kvbase + kvt * 16 + (lane & 15);
                    int q_abs = qbase + wave * 16 + (lane >> 4) * 4 + r;
                    if (kv_abs > q_abs) val = -1e30f;
                }
                s[kvt][r] = val;
            }
        }
        float mnew[4], psum[4], scl[4];
#pragma unroll
        for (int r = 0; r < 4; r++) {
            float mx = fmaxf(fmaxf(s[0][r], s[1][r]), fmaxf(s[2][r], s[3][r]));
#pragma unroll
            for (int o2 = 8; o2 > 0; o2 >>= 1) mx = fmaxf(mx, __shfl_xor(mx, o2));
            mnew[r] = fmaxf(m_run[r], mx);
            float ps = 0.f;
#pragma unroll
            for (int kvt = 0; kvt < 4; kvt++) {
                float p = expf(s[kvt][r] - mnew[r]);
                s[kvt][r] = p;
                ps += p;
            }
#pragma unroll
            for (int o2 = 8; o2 > 0; o2 >>= 1) ps += __shfl_xor(ps, o2);
            psum[r] = ps;
            scl[r] = expf(m_run[r] - mnew[r]);
            m_run[r] = mnew[r];
            l_run[r] = l_run[r] * scl[r] + psum[r];
        }
#pragma unroll
        for (int dt = 0; dt < 4; dt++)
#pragma unroll
            for (int r = 0; r < 4; r++) o[dt][r] *= scl[r];
#pragma unroll
        for (int kvt = 0; kvt < 4; kvt++)
#pragma unroll
            for (int r = 0; r < 4; r++)
                Ps[swz(wave * 16 + (lane >> 4) * 4 + r, kvt * 16 + (lane & 15))] = f2bf(s[kvt][r]);
        __syncthreads();
        bf16x8 pa0 = *(const bf16x8*)&Ps[swz(wave * 16 + (lane & 15), 8 * (lane >> 4))];
        bf16x8 pa1 = *(const bf16x8*)&Ps[swz(wave * 16 + (lane & 15), 32 + 8 * (lane >> 4))];
#pragma unroll
        for (int dt = 0; dt < 4; dt++) {
            bf16x8 vf0 = *(const bf16x8*)&Vs[swz(dt * 16 + (lane & 15), 8 * (lane >> 4))];
            bf16x8 vf1 = *(const bf16x8*)&Vs[swz(dt * 16 + (lane & 15), 32 + 8 * (lane >> 4))];
            o[dt] = __builtin_amdgcn_mfma_f32_16x16x32_bf16(pa0, vf0, o[dt], 0, 0, 0);
            o[dt] = __builtin_amdgcn_mfma_f32_16x16x32_bf16(pa1, vf1, o[dt], 0, 0, 0);
        }
        __syncthreads();
    }
#pragma unroll
    for (int r = 0; r < 4; r++) {
        float inv = 1.0f / l_run[r];
        int qrow = qbase + wave * 16 + (lane >> 4) * 4 + r;
#pragma unroll
        for (int dt = 0; dt < 4; dt++) {
            a[((size_t)(b * SEQ + qrow)) * D + h * DH + dt * 16 + (lane & 15)] = o[dt][r] * inv;
        }
    }
}

// ---------------- routing ----------------
__global__ void routing_kernel(const float* __restrict__ h2, const float* __restrict__ gw,
                               float* __restrict__ probs, int* __restrict__ list,
                               int* __restrict__ counts, float* __restrict__ wtok) {
    int t = blockIdx.x;
    int tid = threadIdx.x; // 64
    __shared__ float part[64][8];
    float l[8] = {0.f, 0.f, 0.f, 0.f, 0.f, 0.f, 0.f, 0.f};
    const float* hr = h2 + (size_t)t * D;
    for (int i = tid; i < D; i += 64) {
        float hv = hr[i];
        const float* g = gw + (size_t)i * E;
#pragma unroll
        for (int e = 0; e < 8; e++) l[e] += hv * g[e];
    }
#pragma unroll
    for (int e = 0; e < 8; e++) part[tid][e] = l[e];
    __syncthreads();
    if (tid == 0) {
        float lg[8];
#pragma unroll
        for (int e = 0; e < 8; e++) {
            float s = 0.f;
            for (int j = 0; j < 64; j++) s += part[j][e];
            lg[e] = s;
        }
        float m = lg[0];
#pragma unroll
        for (int e = 1; e < 8; e++) m = fmaxf(m, lg[e]);
        float se = 0.f;
        float pr[8];
#pragma unroll
        for (int e = 0; e < 8; e++) { pr[e] = expf(lg[e] - m); se += pr[e]; }
#pragma unroll
        for (int e = 0; e < 8; e++) { pr[e] /= se; probs[t * 8 + e] = pr[e]; }
        int i0 = 0;
#pragma unroll
        for (int e = 1; e < 8; e++) if (pr[e] > pr[i0]) i0 = e;
        int i1 = -1;
#pragma unroll
        for (int e = 0; e < 8; e++) {
            if (e == i0) continue;
            if (i1 < 0 || pr[e] > pr[i1]) i1 = e;
        }
        float w0 = pr[i0], w1 = pr[i1];
        float wsum = w0 + w1;
        wtok[t * 2 + 0] = w0 / wsum;
        wtok[t * 2 + 1] = w1 / wsum;
        int p0 = atomicAdd(&counts[i0], 1); list[i0 * T + p0] = t * 2 + 0;
        int p1 = atomicAdd(&counts[i1], 1); list[i1 * T + p1] = t * 2 + 1;
    }
}

// ---------------- aux loss ----------------
__global__ void aux_kernel(const float* __restrict__ probs, const int* __restrict__ counts,
                           float* __restrict__ out_aux) {
    int tid = threadIdx.x;
    __shared__ float ps[8];
    if (tid < 8) {
        float s = 0.f;
        for (int t = 0; t < T; t++) s += probs[t * 8 + tid];
        ps[tid] = s;
    }
    __syncthreads();
    if (tid == 0) {
        float aux = 0.f;
        for (int e = 0; e < 8; e++) {
            float f = (float)counts[e] / (float)T;
            float P = ps[e] / (float)T;
            aux += f * P;
        }
        out_aux[0] = (float)E * aux;
    }
}

// ---- MoE up, MFMA bf16 ----
__global__ __launch_bounds__(256) void moe_up_mfma(
    const float* __restrict__ h2, const float* __restrict__ w1, const float* __restrict__ w3,
    const int* __restrict__ list, const int* __restrict__ counts,
    short* __restrict__ g, int c0) {
    int e = blockIdx.z;
    int n = counts[e];
    int mb = blockIdx.y * 64;
    if (mb >= n) return;
    int nb = blockIdx.x * 64;  // col within chunk
    const float* B1g = w1 + (size_t)e * D * HID + (c0 + nb);
    const float* B3g = w3 + (size_t)e * D * HID + (c0 + nb);
    __shared__ short As[64 * 64];
    __shared__ short B1s[64 * 64];
    __shared__ short B3s[64 * 64];
    __shared__ int rowpid[64];
    __shared__ int rowtok[64];
    int tid = threadIdx.x;
    int lane = tid & 63, wave = tid >> 6;
    int wr = wave >> 1, wc = wave & 1;
    if (tid < 64) {
        int r = mb + tid;
        int pid = (r < n) ? list[e * T + r] : list[e * T];
        rowpid[tid] = pid;
        rowtok[tid] = pid >> 1;
    }
    __syncthreads();

    f32x4 acc1[2][2] = {};
    f32x4 acc3[2][2] = {};
    int ar = tid >> 2, ac = (tid & 3) * 16;
    const float* Arow = h2 + (size_t)rowtok[ar] * D + ac;

    for (int k0 = 0; k0 < D; k0 += 64) {
#pragma unroll
        for (int j = 0; j < 4; j++) {
            float4 v = *(const float4*)(Arow + k0 + j * 4);
            short4 s4 = make_short4(f2bf(v.x), f2bf(v.y), f2bf(v.z), f2bf(v.w));
            *(short4*)&As[swz(ar, ac + j * 4)] = s4;
        }
#pragma unroll
        for (int i = 0; i < 4; i++) {
            int idx = tid + i * 256;
            int kr = idx >> 4, n0 = (idx & 15) * 4;
            float4 v1 = *(const float4*)(B1g + (size_t)(k0 + kr) * HID + n0);
            float4 v3 = *(const float4*)(B3g + (size_t)(k0 + kr) * HID + n0);
            B1s[swz(n0 + 0, kr)] = f2bf(v1.x); B1s[swz(n0 + 1, kr)] = f2bf(v1.y);
            B1s[swz(n0 + 2, kr)] = f2bf(v1.z); B1s[swz(n0 + 3, kr)] = f2bf(v1.w);
            B3s[swz(n0 + 0, kr)] = f2bf(v3.x); B3s[swz(n0 + 1, kr)] = f2bf(v3.y);
            B3s[swz(n0 + 2, kr)] = f2bf(v3.z); B3s[swz(n0 + 3, kr)] = f2bf(v3.w);
        }
        __syncthreads();
#pragma unroll
        for (int kk = 0; kk < 64; kk += 32) {
            int krd = kk + 8 * (lane >> 4);
            bf16x8 a0  = *(const bf16x8*)&As[swz(wr * 32 + (lane & 15), krd)];
            bf16x8 a1  = *(const bf16x8*)&As[swz(wr * 32 + 16 + (lane & 15), krd)];
            bf16x8 b10 = *(const bf16x8*)&B1s[swz(wc * 32 + (lane & 15), krd)];
            bf16x8 b11 = *(const bf16x8*)&B1s[swz(wc * 32 + 16 + (lane & 15), krd)];
            bf16x8 b30 = *(const bf16x8*)&B3s[swz(wc * 32 + (lane & 15), krd)];
            bf16x8 b31 = *(const bf16x8*)&B3s[swz(wc * 32 + 16 + (lane & 15), krd)];
            acc1[0][0] = __builtin_amdgcn_mfma_f32_16x16x32_bf16(a0, b10, acc1[0][0], 0, 0, 0);
            acc1[0][1] = __builtin_amdgcn_mfma_f32_16x16x32_bf16(a0, b11, acc1[0][1], 0, 0, 0);
            acc1[1][0] = __builtin_amdgcn_mfma_f32_16x16x32_bf16(a1, b10, acc1[1][0], 0, 0, 0);
            acc1[1][1] = __builtin_amdgcn_mfma_f32_16x16x32_bf16(a1, b11, acc1[1][1], 0, 0, 0);
            acc3[0][0] = __builtin_amdgcn_mfma_f32_16x16x32_bf16(a0, b30, acc3[0][0], 0, 0, 0);
            acc3[0][1] = __builtin_amdgcn_mfma_f32_16x16x32_bf16(a0, b31, acc3[0][1], 0, 0, 0);
            acc3[1][0] = __builtin_amdgcn_mfma_f32_16x16x32_bf16(a1, b30, acc3[1][0], 0, 0, 0);
            acc3[1][1] = __builtin_amdgcn_mfma_f32_16x16x32_bf16(a1, b31, acc3[1][1], 0, 0, 0);
        }
        __syncthreads();
    }
#pragma unroll
    for (int mi = 0; mi < 2; mi++)
#pragma unroll
        for (int ni = 0; ni < 2; ni++)
#pragma unroll
            for (int r = 0; r < 4; r++) {
                int row = wr * 32 + mi * 16 + (lane >> 4) * 4 + r;
                if (mb + row < n) {
                    int pid = rowpid[row];
                    int col = nb + wc * 32 + ni * 16 + (lane & 15);
                    float v1 = acc1[mi][ni][r], v3 = acc3[mi][ni][r];
                    float sil = v1 / (1.f + expf(-v1));
                    g[(size_t)pid * HC + col] = f2bf(sil * v3);
                }
            }
}

// ---- MoE down, MFMA bf16 ----
__global__ __launch_bounds__(256) void moe_down_mfma(
    const short* __restrict__ g, const float* __restrict__ w2,
    const int* __restrict__ list, const int* __restrict__ counts,
    float* __restrict__ yp, int c0, int first) {
    int e = blockIdx.z;
    int n = counts[e];
    int mb = blockIdx.y * 64;
    if (mb >= n) return;
    int nb = blockIdx.x * 64;
    const float* Bg = w2 + (size_t)e * HID * D + (size_t)c0 * D + nb;
    __shared__ short As[64 * 64];
    __shared__ short Bs[64 * 64];
    __shared__ int rowpid[64];
    int tid = threadIdx.x;
    int lane = tid & 63, wave = tid >> 6;
    int wr = wave >> 1, wc = wave & 1;
    if (tid < 64) {
        int r = mb + tid;
        rowpid[tid] = (r < n) ? list[e * T + r] : list[e * T];
    }
    __syncthreads();

    f32x4 acc[2][2] = {};

    for (int k0 = 0; k0 < HC; k0 += 64) {
#pragma unroll
        for (int i = 0; i < 2; i++) {
            int idx = tid + i * 256;
            int r = idx >> 3, kq = (idx & 7) * 8;
            const short* src = g + (size_t)rowpid[r] * HC + k0 + kq;
            bf16x8 v = *(const bf16x8*)src;
            *(bf16x8*)&As[swz(r, kq)] = v;
        }
#pragma unroll
        for (int i = 0; i < 4; i++) {
            int idx = tid + i * 256;
            int kr = idx >> 4, n0 = (idx & 15) * 4;
            float4 v = *(const float4*)(Bg + (size_t)(k0 + kr) * D + n0);
            Bs[swz(n0 + 0, kr)] = f2bf(v.x); Bs[swz(n0 + 1, kr)] = f2bf(v.y);
            Bs[swz(n0 + 2, kr)] = f2bf(v.z); Bs[swz(n0 + 3, kr)] = f2bf(v.w);
        }
        __syncthreads();
#pragma unroll
        for (int kk = 0; kk < 64; kk += 32) {
            int krd = kk + 8 * (lane >> 4);
            bf16x8 a0 = *(const bf16x8*)&As[swz(wr * 32 + (lane & 15), krd)];
            bf16x8 a1 = *(const bf16x8*)&As[swz(wr * 32 + 16 + (lane & 15), krd)];
            bf16x8 b0 = *(const bf16x8*)&Bs[swz(wc * 32 + (lane & 15), krd)];
            bf16x8 b1 = *(const bf16x8*)&Bs[swz(wc * 32 + 16 + (lane & 15), krd)];
            acc[0][0] = __builtin_amdgcn_mfma_f32_16x16x32_bf16(a0, b0, acc[0][0], 0, 0, 0);
            acc[0][1] = __builtin_amdgcn_mfma_f32_16x16x32_bf16(a0, b1, acc[0][1], 0, 0, 0);
            acc[1][0] = __builtin_amdgcn_mfma_f32_16x16x32_bf16(a1, b0, acc[1][0], 0, 0, 0);
            acc[1][1] = __builtin_amdgcn_mfma_f32_16x16x32_bf16(a1, b1, acc[1][1], 0, 0, 0);
        }
        __syncthreads();
    }
#pragma unroll
    for (int mi = 0; mi < 2; mi++)
#pragma unroll
        for (int ni = 0; ni < 2; ni++)
#pragma unroll
            for (int r = 0; r < 4; r++) {
                int row = wr * 32 + mi * 16 + (lane >> 4) * 4 + r;
                if (mb + row < n) {
                    int pid = rowpid[row];
                    int col = nb + wc * 32 + ni * 16 + (lane & 15);
                    size_t o = (size_t)pid * D + col;
                    yp[o] = first ? acc[mi][ni][r] : (yp[o] + acc[mi][ni][r]);
                }
            }
}

// ---------------- final combine ----------------
__global__ void combine_kernel(const float* __restrict__ yp, const float* __restrict__ wtok,
                               float* __restrict__ out) {
    int idx = blockIdx.x * 256 + threadIdx.x; // T * (D/4)
    if (idx >= T * (D / 4)) return;
    int t = idx / (D / 4);
    int d4 = idx % (D / 4);
    float4 a = ((const float4*)(out + (size_t)t * D))[d4];
    float4 y0 = ((const float4*)(yp + (size_t)(2 * t) * D))[d4];
    float4 y1 = ((const float4*)(yp + (size_t)(2 * t + 1) * D))[d4];
    float w0 = wtok[2 * t], w1 = wtok[2 * t + 1];
    a.x += w0 * y0.x + w1 * y1.x;
    a.y += w0 * y0.y + w1 * y1.y;
    a.z += w0 * y0.z + w1 * y1.z;
    a.w += w0 * y0.w + w1 * y1.w;
    ((float4*)(out + (size_t)t * D))[d4] = a;
}

extern "C" void kernel_launch(void* const* d_in, const int* in_sizes, int n_in,
                              void* d_out, int out_size, void* d_ws, size_t ws_size,
                              hipStream_t stream) {
    const float* x    = (const float*)d_in[0];
    const float* n1w  = (const float*)d_in[1];
    const float* n2w  = (const float*)d_in[2];
    const float* wq   = (const float*)d_in[3];
    const float* wdkv = (const float*)d_in[4];
    const float* wuk  = (const float*)d_in[5];
    const float* wuv  = (const float*)d_in[6];
    const float* wo   = (const float*)d_in[7];
    const float* gw   = (const float*)d_in[8];
    const float* w1   = (const float*)d_in[9];
    const float* w2   = (const float*)d_in[10];
    const float* w3   = (const float*)d_in[11];
    const int*   sp   = (const int*)d_in[12];
    float* out = (float*)d_out;

    // ws layout (floats). Total ~15.0 MB.
    float* ws = (float*)d_ws;
    float* A_  = ws + 0;                 // 786432: qb, later h2b
    float* B_  = ws + 786432;            // 786432: kb, later yp[0..]
    float* C_  = ws + 1572864;           // 786432: vb, later yp[..]
    float* Dd  = ws + 2359296;           // 786432: h, later ab
    float* cb  = ws + 3145728;           // 65536
    float* probs = ws + 3211264;         // 8192
    float* wtok  = ws + 3219456;         // 2048
    int*   list  = (int*)(ws + 3221504); // 8192 ints
    int*   counts= (int*)(ws + 3229696); // 16 ints
    short* gch   = (short*)(ws + 3229712); // 2T*HC bf16 = 2 MB
    float* yp = B_;                      // 2T*D fp32 (B_ and C_ contiguous)

    hipMemsetAsync(counts, 0, 16 * sizeof(int), stream);

    // ---- attention ----
    rmsnorm_kernel<<<T, 256, 0, stream>>>(x, n1w, Dd);                                       // h
    gemm_bf16<false><<<dim3(D / 64, T / 64), 256, 0, stream>>>(Dd, wq, nullptr, A_, T, D, D);    // qb
    gemm_bf16<false><<<dim3(1, T / 64), 256, 0, stream>>>(Dd, wdkv, nullptr, cb, T, DL, D);      // c
    gemm_kuv<<<dim3(D / 64, T / 64), 256, 0, stream>>>(cb, wuk, wuv, B_, C_, T, D, DL);          // kb, vb
    rope_kernel<<<(T * H * 32 + 255) / 256, 256, 0, stream>>>(A_, B_, sp);
    attn_mfma<<<dim3(8, H, BATCH), 256, 0, stream>>>(A_, B_, C_, Dd);                        // ab
    gemm_bf16<true><<<dim3(D / 64, T / 64), 256, 0, stream>>>(Dd, wo, x, out, T, D, D);      // x1 in out

    // ---- MoE ----
    rmsnorm_kernel<<<T, 256, 0, stream>>>(out, n2w, A_);                                     // h2
    routing_kernel<<<T, 64, 0, stream>>>(A_, gw, probs, list, counts, wtok);
    aux_kernel<<<1, 256, 0, stream>>>(probs, counts, out + (out_size - 1));
    for (int c0 = 0; c0 < HID; c0 += HC) {
        moe_up_mfma<<<dim3(HC / 64, T / 64, E), 256, 0, stream>>>(A_, w1, w3, list, counts, gch, c0);
        moe_down_mfma<<<dim3(D / 64, T / 64, E), 256, 0, stream>>>(gch, w2, list, counts, yp, c0, c0 == 0 ? 1 : 0);
    }
    combine_kernel<<<(T * (D / 4) + 255) / 256, 256, 0, stream>>>(yp, wtok, out);
}

// Round 9
// 365.280 us; speedup vs baseline: 4.0235x; 1.4710x over previous
//
#include <hip/hip_runtime.h>
#include <hip/hip_bf16.h>
#include <math.h>

#define T 1024
#define SEQ 512
#define BATCH 2
#define D 768
#define H 12
#define DH 64
#define DL 64
#define E 8
#define HID 3072
#define HC 1024   // HID chunk for MoE g materialization

typedef __attribute__((ext_vector_type(8))) short bf16x8;
typedef __attribute__((ext_vector_type(4))) float f32x4;

// fp32 -> bf16 RNE via compiler (emits v_cvt_pk_bf16_f32 for pairs)
__device__ inline short f2bf(float f) {
    __hip_bfloat16 h = __float2bfloat16(f);
    return *reinterpret_cast<short*>(&h);
}

// attn swizzle (unchanged, validated)
__device__ inline int swz(int row, int k) { return (row * 64 + k) ^ ((row & 7) << 3); }
// GEMM swizzle: XOR row bits 1..3 into k bits 3..5 (16B granules).
// Transpose-writes (rows 4q+j concurrent) -> 4-way; fragment reads (rows 16s+n) -> 2-way.
__device__ inline int swzB(int row, int k) { return row * 64 + (k ^ (((row >> 1) & 7) << 3)); }

// ---------------- rmsnorm ----------------
__global__ void rmsnorm_kernel(const float* __restrict__ x, const float* __restrict__ w,
                               float* __restrict__ out) {
    int t = blockIdx.x;
    int tid = threadIdx.x; // 256
    const float* xr = x + (size_t)t * D;
    float s = 0.f;
    for (int i = tid; i < D; i += 256) { float v = xr[i]; s += v * v; }
    __shared__ float red[256];
    red[tid] = s; __syncthreads();
    for (int o = 128; o > 0; o >>= 1) { if (tid < o) red[tid] += red[tid + o]; __syncthreads(); }
    float scale = 1.0f / sqrtf(red[0] / (float)D + 1e-6f);
    for (int i = tid; i < D; i += 256) out[(size_t)t * D + i] = xr[i] * scale * w[i];
}

// ---------------- dense bf16 MFMA GEMM: C = A@B (+R). 64|M,N,K ----------------
template<bool RES>
__global__ __launch_bounds__(256) void gemm_bf16(
    const float* __restrict__ A, const float* __restrict__ B,
    const float* __restrict__ Rp, float* __restrict__ C,
    int M, int N, int K) {
    int mb = blockIdx.y * 64, nb = blockIdx.x * 64;
    __shared__ short As[64 * 64];
    __shared__ short Bs[64 * 64];
    int tid = threadIdx.x;
    int lane = tid & 63, wave = tid >> 6;
    int wr = wave >> 1, wc = wave & 1;
    f32x4 acc[2][2] = {};
    int ar = tid >> 2, ac = (tid & 3) * 16;
    int bn = (tid & 15) * 4, bk = (tid >> 4) * 4;
    const float* Arow = A + (size_t)(mb + ar) * K + ac;
    const float* Bg = B + nb;
    float4 a_c[4], b_c[4];
#pragma unroll
    for (int j = 0; j < 4; j++) a_c[j] = *(const float4*)(Arow + j * 4);
#pragma unroll
    for (int i = 0; i < 4; i++) b_c[i] = *(const float4*)(Bg + (size_t)(bk + i) * N + bn);
    for (int k0 = 0; k0 < K; k0 += 64) {
        float4 a_n[4], b_n[4];
        bool more = (k0 + 64) < K;
        if (more) {
#pragma unroll
            for (int j = 0; j < 4; j++) a_n[j] = *(const float4*)(Arow + k0 + 64 + j * 4);
#pragma unroll
            for (int i = 0; i < 4; i++) b_n[i] = *(const float4*)(Bg + (size_t)(k0 + 64 + bk + i) * N + bn);
        }
#pragma unroll
        for (int j = 0; j < 4; j++)
            *(short4*)&As[swzB(ar, ac + j * 4)] =
                make_short4(f2bf(a_c[j].x), f2bf(a_c[j].y), f2bf(a_c[j].z), f2bf(a_c[j].w));
        *(short4*)&Bs[swzB(bn + 0, bk)] = make_short4(f2bf(b_c[0].x), f2bf(b_c[1].x), f2bf(b_c[2].x), f2bf(b_c[3].x));
        *(short4*)&Bs[swzB(bn + 1, bk)] = make_short4(f2bf(b_c[0].y), f2bf(b_c[1].y), f2bf(b_c[2].y), f2bf(b_c[3].y));
        *(short4*)&Bs[swzB(bn + 2, bk)] = make_short4(f2bf(b_c[0].z), f2bf(b_c[1].z), f2bf(b_c[2].z), f2bf(b_c[3].z));
        *(short4*)&Bs[swzB(bn + 3, bk)] = make_short4(f2bf(b_c[0].w), f2bf(b_c[1].w), f2bf(b_c[2].w), f2bf(b_c[3].w));
        __syncthreads();
#pragma unroll
        for (int kk = 0; kk < 64; kk += 32) {
            int krd = kk + 8 * (lane >> 4);
            bf16x8 a0 = *(const bf16x8*)&As[swzB(wr * 32 + (lane & 15), krd)];
            bf16x8 a1 = *(const bf16x8*)&As[swzB(wr * 32 + 16 + (lane & 15), krd)];
            bf16x8 b0 = *(const bf16x8*)&Bs[swzB(wc * 32 + (lane & 15), krd)];
            bf16x8 b1 = *(const bf16x8*)&Bs[swzB(wc * 32 + 16 + (lane & 15), krd)];
            acc[0][0] = __builtin_amdgcn_mfma_f32_16x16x32_bf16(a0, b0, acc[0][0], 0, 0, 0);
            acc[0][1] = __builtin_amdgcn_mfma_f32_16x16x32_bf16(a0, b1, acc[0][1], 0, 0, 0);
            acc[1][0] = __builtin_amdgcn_mfma_f32_16x16x32_bf16(a1, b0, acc[1][0], 0, 0, 0);
            acc[1][1] = __builtin_amdgcn_mfma_f32_16x16x32_bf16(a1, b1, acc[1][1], 0, 0, 0);
        }
        __syncthreads();
        if (more) {
#pragma unroll
            for (int j = 0; j < 4; j++) { a_c[j] = a_n[j]; b_c[j] = b_n[j]; }
        }
    }
#pragma unroll
    for (int mi = 0; mi < 2; mi++)
#pragma unroll
        for (int ni = 0; ni < 2; ni++)
#pragma unroll
            for (int r = 0; r < 4; r++) {
                int row = mb + wr * 32 + mi * 16 + (lane >> 4) * 4 + r;
                int col = nb + wc * 32 + ni * 16 + (lane & 15);
                float val = acc[mi][ni][r];
                if (RES) val += Rp[(size_t)row * N + col];
                C[(size_t)row * N + col] = val;
            }
}

// ---- fused K/V up-projection: kb = cb@wuk, vb = cb@wuv (K=DL=64, single K-step) ----
__global__ __launch_bounds__(256) void gemm_kuv(
    const float* __restrict__ A, const float* __restrict__ Bk, const float* __restrict__ Bv,
    float* __restrict__ Ck, float* __restrict__ Cv, int M, int N, int K) {
    int mb = blockIdx.y * 64, nb = blockIdx.x * 64;
    __shared__ short As[64 * 64];
    __shared__ short B1s[64 * 64];
    __shared__ short B2s[64 * 64];
    int tid = threadIdx.x;
    int lane = tid & 63, wave = tid >> 6;
    int wr = wave >> 1, wc = wave & 1;
    f32x4 acc1[2][2] = {};
    f32x4 acc2[2][2] = {};
    int ar = tid >> 2, ac = (tid & 3) * 16;
    int bn = (tid & 15) * 4, bk = (tid >> 4) * 4;
    const float* Arow = A + (size_t)(mb + ar) * K + ac;
    {
        float4 a_c[4], p_c[4], q_c[4];
#pragma unroll
        for (int j = 0; j < 4; j++) a_c[j] = *(const float4*)(Arow + j * 4);
#pragma unroll
        for (int i = 0; i < 4; i++) {
            p_c[i] = *(const float4*)(Bk + (size_t)(bk + i) * N + nb + bn);
            q_c[i] = *(const float4*)(Bv + (size_t)(bk + i) * N + nb + bn);
        }
#pragma unroll
        for (int j = 0; j < 4; j++)
            *(short4*)&As[swzB(ar, ac + j * 4)] =
                make_short4(f2bf(a_c[j].x), f2bf(a_c[j].y), f2bf(a_c[j].z), f2bf(a_c[j].w));
        *(short4*)&B1s[swzB(bn + 0, bk)] = make_short4(f2bf(p_c[0].x), f2bf(p_c[1].x), f2bf(p_c[2].x), f2bf(p_c[3].x));
        *(short4*)&B1s[swzB(bn + 1, bk)] = make_short4(f2bf(p_c[0].y), f2bf(p_c[1].y), f2bf(p_c[2].y), f2bf(p_c[3].y));
        *(short4*)&B1s[swzB(bn + 2, bk)] = make_short4(f2bf(p_c[0].z), f2bf(p_c[1].z), f2bf(p_c[2].z), f2bf(p_c[3].z));
        *(short4*)&B1s[swzB(bn + 3, bk)] = make_short4(f2bf(p_c[0].w), f2bf(p_c[1].w), f2bf(p_c[2].w), f2bf(p_c[3].w));
        *(short4*)&B2s[swzB(bn + 0, bk)] = make_short4(f2bf(q_c[0].x), f2bf(q_c[1].x), f2bf(q_c[2].x), f2bf(q_c[3].x));
        *(short4*)&B2s[swzB(bn + 1, bk)] = make_short4(f2bf(q_c[0].y), f2bf(q_c[1].y), f2bf(q_c[2].y), f2bf(q_c[3].y));
        *(short4*)&B2s[swzB(bn + 2, bk)] = make_short4(f2bf(q_c[0].z), f2bf(q_c[1].z), f2bf(q_c[2].z), f2bf(q_c[3].z));
        *(short4*)&B2s[swzB(bn + 3, bk)] = make_short4(f2bf(q_c[0].w), f2bf(q_c[1].w), f2bf(q_c[2].w), f2bf(q_c[3].w));
    }
    __syncthreads();
#pragma unroll
    for (int kk = 0; kk < 64; kk += 32) {
        int krd = kk + 8 * (lane >> 4);
        bf16x8 a0 = *(const bf16x8*)&As[swzB(wr * 32 + (lane & 15), krd)];
        bf16x8 a1 = *(const bf16x8*)&As[swzB(wr * 32 + 16 + (lane & 15), krd)];
        bf16x8 p0 = *(const bf16x8*)&B1s[swzB(wc * 32 + (lane & 15), krd)];
        bf16x8 p1 = *(const bf16x8*)&B1s[swzB(wc * 32 + 16 + (lane & 15), krd)];
        bf16x8 q0 = *(const bf16x8*)&B2s[swzB(wc * 32 + (lane & 15), krd)];
        bf16x8 q1 = *(const bf16x8*)&B2s[swzB(wc * 32 + 16 + (lane & 15), krd)];
        acc1[0][0] = __builtin_amdgcn_mfma_f32_16x16x32_bf16(a0, p0, acc1[0][0], 0, 0, 0);
        acc1[0][1] = __builtin_amdgcn_mfma_f32_16x16x32_bf16(a0, p1, acc1[0][1], 0, 0, 0);
        acc1[1][0] = __builtin_amdgcn_mfma_f32_16x16x32_bf16(a1, p0, acc1[1][0], 0, 0, 0);
        acc1[1][1] = __builtin_amdgcn_mfma_f32_16x16x32_bf16(a1, p1, acc1[1][1], 0, 0, 0);
        acc2[0][0] = __builtin_amdgcn_mfma_f32_16x16x32_bf16(a0, q0, acc2[0][0], 0, 0, 0);
        acc2[0][1] = __builtin_amdgcn_mfma_f32_16x16x32_bf16(a0, q1, acc2[0][1], 0, 0, 0);
        acc2[1][0] = __builtin_amdgcn_mfma_f32_16x16x32_bf16(a1, q0, acc2[1][0], 0, 0, 0);
        acc2[1][1] = __builtin_amdgcn_mfma_f32_16x16x32_bf16(a1, q1, acc2[1][1], 0, 0, 0);
    }
#pragma unroll
    for (int mi = 0; mi < 2; mi++)
#pragma unroll
        for (int ni = 0; ni < 2; ni++)
#pragma unroll
            for (int r = 0; r < 4; r++) {
                int row = mb + wr * 32 + mi * 16 + (lane >> 4) * 4 + r;
                int col = nb + wc * 32 + ni * 16 + (lane & 15);
                Ck[(size_t)row * N + col] = acc1[mi][ni][r];
                Cv[(size_t)row * N + col] = acc2[mi][ni][r];
            }
}

// ---------------- RoPE (in-place on q and k) ----------------
__global__ void rope_kernel(float* __restrict__ qb, float* __restrict__ kb,
                            const int* __restrict__ spp) {
    int p = blockIdx.x * 256 + threadIdx.x; // T*H*32
    if (p >= T * H * 32) return;
    int i = p & 31;
    int rem = p >> 5;
    int h = rem % H;
    int ts = rem / H;
    int s = ts % SEQ;
    float invf = powf(10000.0f, -(float)(2 * i) / 64.0f);
    float ang = (float)(s + spp[0]) * invf;
    float c = cosf(ang), sn = sinf(ang);
    size_t base = (size_t)ts * D + h * DH;
    float x1 = qb[base + i], x2 = qb[base + 32 + i];
    qb[base + i] = x1 * c - x2 * sn;
    qb[base + 32 + i] = x1 * sn + x2 * c;
    x1 = kb[base + i]; x2 = kb[base + 32 + i];
    kb[base + i] = x1 * c - x2 * sn;
    kb[base + 32 + i] = x1 * sn + x2 * c;
}

// ---------------- flash attention, MFMA bf16 (unchanged) ----------------
__global__ __launch_bounds__(256) void attn_mfma(
    const float* __restrict__ q, const float* __restrict__ k,
    const float* __restrict__ v, float* __restrict__ a) {
    int qt = blockIdx.x, h = blockIdx.y, b = blockIdx.z;
    int tid = threadIdx.x, lane = tid & 63, wave = tid >> 6;
    __shared__ short Qs[64 * 64];
    __shared__ short Ks[64 * 64];
    __shared__ short Vs[64 * 64];
    __shared__ short Ps[64 * 64];
    int qbase = qt * 64;
    {
        int r = tid >> 2, d0 = (tid & 3) * 16;
        const float* src = q + ((size_t)(b * SEQ + qbase + r)) * D + h * DH + d0;
#pragma unroll
        for (int j = 0; j < 4; j++) {
            float4 vv = *(const float4*)(src + j * 4);
            *(short4*)&Qs[swz(r, d0 + j * 4)] =
                make_short4(f2bf(vv.x), f2bf(vv.y), f2bf(vv.z), f2bf(vv.w));
        }
    }
    __syncthreads();
    bf16x8 qf0 = *(const bf16x8*)&Qs[swz(wave * 16 + (lane & 15), 8 * (lane >> 4))];
    bf16x8 qf1 = *(const bf16x8*)&Qs[swz(wave * 16 + (lane & 15), 32 + 8 * (lane >> 4))];

    float m_run[4] = {-1e30f, -1e30f, -1e30f, -1e30f};
    float l_run[4] = {0.f, 0.f, 0.f, 0.f};
    f32x4 o[4] = {};

    for (int kt = 0; kt <= qt; kt++) {
        int kvbase = kt * 64;
        {
            int r = tid >> 2, d0 = (tid & 3) * 16;
            const float* src = k + ((size_t)(b * SEQ + kvbase + r)) * D + h * DH + d0;
#pragma unroll
            for (int j = 0; j < 4; j++) {
                float4 vv = *(const float4*)(src + j * 4);
                *(short4*)&Ks[swz(r, d0 + j * 4)] =
                    make_short4(f2bf(vv.x), f2bf(vv.y), f2bf(vv.z), f2bf(vv.w));
            }
        }
#pragma unroll
        for (int i = 0; i < 4; i++) {
            int idx = tid + i * 256;
            int kr = idx >> 4, d0 = (idx & 15) * 4;
            float4 vv = *(const float4*)(v + ((size_t)(b * SEQ + kvbase + kr)) * D + h * DH + d0);
            Vs[swz(d0 + 0, kr)] = f2bf(vv.x); Vs[swz(d0 + 1, kr)] = f2bf(vv.y);
            Vs[swz(d0 + 2, kr)] = f2bf(vv.z); Vs[swz(d0 + 3, kr)] = f2bf(vv.w);
        }
        __syncthreads();

        f32x4 s[4];
#pragma unroll
        for (int kvt = 0; kvt < 4; kvt++) {
            bf16x8 kf0 = *(const bf16x8*)&Ks[swz(kvt * 16 + (lane & 15), 8 * (lane >> 4))];
            bf16x8 kf1 = *(const bf16x8*)&Ks[swz(kvt * 16 + (lane & 15), 32 + 8 * (lane >> 4))];
            f32x4 z = {};
            z = __builtin_amdgcn_mfma_f32_16x16x32_bf16(qf0, kf0, z, 0, 0, 0);
            z = __builtin_amdgcn_mfma_f32_16x16x32_bf16(qf1, kf1, z, 0, 0, 0);
            s[kvt] = z;
        }
#pragma unroll
        for (int kvt = 0; kvt < 4; kvt++) {
#pragma unroll
            for (int r = 0; r < 4; r++) {
                float val = s[kvt][r] * 0.125f;
                if (kt == qt) {
                    int kv_abs = kvbase + kvt * 16 + (lane & 15);
                    int q_abs = qbase + wave * 16 + (lane >> 4) * 4 + r;
                    if (kv_abs > q_abs) val = -1e30f;
                }
                s[kvt][r] = val;
            }
        }
        float mnew[4], psum[4], scl[4];
#pragma unroll
        for (int r = 0; r < 4; r++) {
            float mx = fmaxf(fmaxf(s[0][r], s[1][r]), fmaxf(s[2][r], s[3][r]));
#pragma unroll
            for (int o2 = 8; o2 > 0; o2 >>= 1) mx = fmaxf(mx, __shfl_xor(mx, o2));
            mnew[r] = fmaxf(m_run[r], mx);
            float ps = 0.f;
#pragma unroll
            for (int kvt = 0; kvt < 4; kvt++) {
                float p = expf(s[kvt][r] - mnew[r]);
                s[kvt][r] = p;
                ps += p;
            }
#pragma unroll
            for (int o2 = 8; o2 > 0; o2 >>= 1) ps += __shfl_xor(ps, o2);
            psum[r] = ps;
            scl[r] = expf(m_run[r] - mnew[r]);
            m_run[r] = mnew[r];
            l_run[r] = l_run[r] * scl[r] + psum[r];
        }
#pragma unroll
        for (int dt = 0; dt < 4; dt++)
#pragma unroll
            for (int r = 0; r < 4; r++) o[dt][r] *= scl[r];
#pragma unroll
        for (int kvt = 0; kvt < 4; kvt++)
#pragma unroll
            for (int r = 0; r < 4; r++)
                Ps[swz(wave * 16 + (lane >> 4) * 4 + r, kvt * 16 + (lane & 15))] = f2bf(s[kvt][r]);
        __syncthreads();
        bf16x8 pa0 = *(const bf16x8*)&Ps[swz(wave * 16 + (lane & 15), 8 * (lane >> 4))];
        bf16x8 pa1 = *(const bf16x8*)&Ps[swz(wave * 16 + (lane & 15), 32 + 8 * (lane >> 4))];
#pragma unroll
        for (int dt = 0; dt < 4; dt++) {
            bf16x8 vf0 = *(const bf16x8*)&Vs[swz(dt * 16 + (lane & 15), 8 * (lane >> 4))];
            bf16x8 vf1 = *(const bf16x8*)&Vs[swz(dt * 16 + (lane & 15), 32 + 8 * (lane >> 4))];
            o[dt] = __builtin_amdgcn_mfma_f32_16x16x32_bf16(pa0, vf0, o[dt], 0, 0, 0);
            o[dt] = __builtin_amdgcn_mfma_f32_16x16x32_bf16(pa1, vf1, o[dt], 0, 0, 0);
        }
        __syncthreads();
    }
#pragma unroll
    for (int r = 0; r < 4; r++) {
        float inv = 1.0f / l_run[r];
        int qrow = qbase + wave * 16 + (lane >> 4) * 4 + r;
#pragma unroll
        for (int dt = 0; dt < 4; dt++) {
            a[((size_t)(b * SEQ + qrow)) * D + h * DH + dt * 16 + (lane & 15)] = o[dt][r] * inv;
        }
    }
}

// ---------------- routing ----------------
__global__ void routing_kernel(const float* __restrict__ h2, const float* __restrict__ gw,
                               float* __restrict__ probs, int* __restrict__ list,
                               int* __restrict__ counts, float* __restrict__ wtok) {
    int t = blockIdx.x;
    int tid = threadIdx.x; // 64
    __shared__ float part[64][8];
    float l[8] = {0.f, 0.f, 0.f, 0.f, 0.f, 0.f, 0.f, 0.f};
    const float* hr = h2 + (size_t)t * D;
    for (int i = tid; i < D; i += 64) {
        float hv = hr[i];
        const float* g = gw + (size_t)i * E;
#pragma unroll
        for (int e = 0; e < 8; e++) l[e] += hv * g[e];
    }
#pragma unroll
    for (int e = 0; e < 8; e++) part[tid][e] = l[e];
    __syncthreads();
    if (tid == 0) {
        float lg[8];
#pragma unroll
        for (int e = 0; e < 8; e++) {
            float s = 0.f;
            for (int j = 0; j < 64; j++) s += part[j][e];
            lg[e] = s;
        }
        float m = lg[0];
#pragma unroll
        for (int e = 1; e < 8; e++) m = fmaxf(m, lg[e]);
        float se = 0.f;
        float pr[8];
#pragma unroll
        for (int e = 0; e < 8; e++) { pr[e] = expf(lg[e] - m); se += pr[e]; }
#pragma unroll
        for (int e = 0; e < 8; e++) { pr[e] /= se; probs[t * 8 + e] = pr[e]; }
        int i0 = 0;
#pragma unroll
        for (int e = 1; e < 8; e++) if (pr[e] > pr[i0]) i0 = e;
        int i1 = -1;
#pragma unroll
        for (int e = 0; e < 8; e++) {
            if (e == i0) continue;
            if (i1 < 0 || pr[e] > pr[i1]) i1 = e;
        }
        float w0 = pr[i0], w1 = pr[i1];
        float wsum = w0 + w1;
        wtok[t * 2 + 0] = w0 / wsum;
        wtok[t * 2 + 1] = w1 / wsum;
        int p0 = atomicAdd(&counts[i0], 1); list[i0 * T + p0] = t * 2 + 0;
        int p1 = atomicAdd(&counts[i1], 1); list[i1 * T + p1] = t * 2 + 1;
    }
}

// ---------------- aux loss ----------------
__global__ void aux_kernel(const float* __restrict__ probs, const int* __restrict__ counts,
                           float* __restrict__ out_aux) {
    int tid = threadIdx.x;
    __shared__ float ps[8];
    if (tid < 8) {
        float s = 0.f;
        for (int t = 0; t < T; t++) s += probs[t * 8 + tid];
        ps[tid] = s;
    }
    __syncthreads();
    if (tid == 0) {
        float aux = 0.f;
        for (int e = 0; e < 8; e++) {
            float f = (float)counts[e] / (float)T;
            float P = ps[e] / (float)T;
            aux += f * P;
        }
        out_aux[0] = (float)E * aux;
    }
}

// ---- MoE up, MFMA bf16, reg-transpose staging + prefetch ----
__global__ __launch_bounds__(256) void moe_up_mfma(
    const float* __restrict__ h2, const float* __restrict__ w1, const float* __restrict__ w3,
    const int* __restrict__ list, const int* __restrict__ counts,
    short* __restrict__ g, int c0) {
    int e = blockIdx.z;
    int n = counts[e];
    int mb = blockIdx.y * 64;
    if (mb >= n) return;
    int nb = blockIdx.x * 64;  // col within chunk
    const float* B1g = w1 + (size_t)e * D * HID + (c0 + nb);
    const float* B3g = w3 + (size_t)e * D * HID + (c0 + nb);
    __shared__ short As[64 * 64];
    __shared__ short B1s[64 * 64];
    __shared__ short B3s[64 * 64];
    __shared__ int rowpid[64];
    __shared__ int rowtok[64];
    int tid = threadIdx.x;
    int lane = tid & 63, wave = tid >> 6;
    int wr = wave >> 1, wc = wave & 1;
    if (tid < 64) {
        int r = mb + tid;
        int pid = (r < n) ? list[e * T + r] : list[e * T];
        rowpid[tid] = pid;
        rowtok[tid] = pid >> 1;
    }
    __syncthreads();

    f32x4 acc1[2][2] = {};
    f32x4 acc3[2][2] = {};
    int ar = tid >> 2, ac = (tid & 3) * 16;
    int bn = (tid & 15) * 4, bk = (tid >> 4) * 4;
    const float* Arow = h2 + (size_t)rowtok[ar] * D + ac;

    float4 a_c[4], b1_c[4], b3_c[4];
#pragma unroll
    for (int j = 0; j < 4; j++) a_c[j] = *(const float4*)(Arow + j * 4);
#pragma unroll
    for (int i = 0; i < 4; i++) {
        b1_c[i] = *(const float4*)(B1g + (size_t)(bk + i) * HID + bn);
        b3_c[i] = *(const float4*)(B3g + (size_t)(bk + i) * HID + bn);
    }
    for (int k0 = 0; k0 < D; k0 += 64) {
        float4 a_n[4], b1_n[4], b3_n[4];
        bool more = (k0 + 64) < D;
        if (more) {
#pragma unroll
            for (int j = 0; j < 4; j++) a_n[j] = *(const float4*)(Arow + k0 + 64 + j * 4);
#pragma unroll
            for (int i = 0; i < 4; i++) {
                b1_n[i] = *(const float4*)(B1g + (size_t)(k0 + 64 + bk + i) * HID + bn);
                b3_n[i] = *(const float4*)(B3g + (size_t)(k0 + 64 + bk + i) * HID + bn);
            }
        }
#pragma unroll
        for (int j = 0; j < 4; j++)
            *(short4*)&As[swzB(ar, ac + j * 4)] =
                make_short4(f2bf(a_c[j].x), f2bf(a_c[j].y), f2bf(a_c[j].z), f2bf(a_c[j].w));
        *(short4*)&B1s[swzB(bn + 0, bk)] = make_short4(f2bf(b1_c[0].x), f2bf(b1_c[1].x), f2bf(b1_c[2].x), f2bf(b1_c[3].x));
        *(short4*)&B1s[swzB(bn + 1, bk)] = make_short4(f2bf(b1_c[0].y), f2bf(b1_c[1].y), f2bf(b1_c[2].y), f2bf(b1_c[3].y));
        *(short4*)&B1s[swzB(bn + 2, bk)] = make_short4(f2bf(b1_c[0].z), f2bf(b1_c[1].z), f2bf(b1_c[2].z), f2bf(b1_c[3].z));
        *(short4*)&B1s[swzB(bn + 3, bk)] = make_short4(f2bf(b1_c[0].w), f2bf(b1_c[1].w), f2bf(b1_c[2].w), f2bf(b1_c[3].w));
        *(short4*)&B3s[swzB(bn + 0, bk)] = make_short4(f2bf(b3_c[0].x), f2bf(b3_c[1].x), f2bf(b3_c[2].x), f2bf(b3_c[3].x));
        *(short4*)&B3s[swzB(bn + 1, bk)] = make_short4(f2bf(b3_c[0].y), f2bf(b3_c[1].y), f2bf(b3_c[2].y), f2bf(b3_c[3].y));
        *(short4*)&B3s[swzB(bn + 2, bk)] = make_short4(f2bf(b3_c[0].z), f2bf(b3_c[1].z), f2bf(b3_c[2].z), f2bf(b3_c[3].z));
        *(short4*)&B3s[swzB(bn + 3, bk)] = make_short4(f2bf(b3_c[0].w), f2bf(b3_c[1].w), f2bf(b3_c[2].w), f2bf(b3_c[3].w));
        __syncthreads();
#pragma unroll
        for (int kk = 0; kk < 64; kk += 32) {
            int krd = kk + 8 * (lane >> 4);
            bf16x8 a0  = *(const bf16x8*)&As[swzB(wr * 32 + (lane & 15), krd)];
            bf16x8 a1  = *(const bf16x8*)&As[swzB(wr * 32 + 16 + (lane & 15), krd)];
            bf16x8 b10 = *(const bf16x8*)&B1s[swzB(wc * 32 + (lane & 15), krd)];
            bf16x8 b11 = *(const bf16x8*)&B1s[swzB(wc * 32 + 16 + (lane & 15), krd)];
            bf16x8 b30 = *(const bf16x8*)&B3s[swzB(wc * 32 + (lane & 15), krd)];
            bf16x8 b31 = *(const bf16x8*)&B3s[swzB(wc * 32 + 16 + (lane & 15), krd)];
            acc1[0][0] = __builtin_amdgcn_mfma_f32_16x16x32_bf16(a0, b10, acc1[0][0], 0, 0, 0);
            acc1[0][1] = __builtin_amdgcn_mfma_f32_16x16x32_bf16(a0, b11, acc1[0][1], 0, 0, 0);
            acc1[1][0] = __builtin_amdgcn_mfma_f32_16x16x32_bf16(a1, b10, acc1[1][0], 0, 0, 0);
            acc1[1][1] = __builtin_amdgcn_mfma_f32_16x16x32_bf16(a1, b11, acc1[1][1], 0, 0, 0);
            acc3[0][0] = __builtin_amdgcn_mfma_f32_16x16x32_bf16(a0, b30, acc3[0][0], 0, 0, 0);
            acc3[0][1] = __builtin_amdgcn_mfma_f32_16x16x32_bf16(a0, b31, acc3[0][1], 0, 0, 0);
            acc3[1][0] = __builtin_amdgcn_mfma_f32_16x16x32_bf16(a1, b30, acc3[1][0], 0, 0, 0);
            acc3[1][1] = __builtin_amdgcn_mfma_f32_16x16x32_bf16(a1, b31, acc3[1][1], 0, 0, 0);
        }
        __syncthreads();
        if (more) {
#pragma unroll
            for (int j = 0; j < 4; j++) { a_c[j] = a_n[j]; b1_c[j] = b1_n[j]; b3_c[j] = b3_n[j]; }
        }
    }
#pragma unroll
    for (int mi = 0; mi < 2; mi++)
#pragma unroll
        for (int ni = 0; ni < 2; ni++)
#pragma unroll
            for (int r = 0; r < 4; r++) {
                int row = wr * 32 + mi * 16 + (lane >> 4) * 4 + r;
                if (mb + row < n) {
                    int pid = rowpid[row];
                    int col = nb + wc * 32 + ni * 16 + (lane & 15);
                    float v1 = acc1[mi][ni][r], v3 = acc3[mi][ni][r];
                    float sil = v1 / (1.f + expf(-v1));
                    g[(size_t)pid * HC + col] = f2bf(sil * v3);
                }
            }
}

// ---- MoE down, MFMA bf16, reg-transpose staging + prefetch ----
__global__ __launch_bounds__(256) void moe_down_mfma(
    const short* __restrict__ g, const float* __restrict__ w2,
    const int* __restrict__ list, const int* __restrict__ counts,
    float* __restrict__ yp, int c0, int first) {
    int e = blockIdx.z;
    int n = counts[e];
    int mb = blockIdx.y * 64;
    if (mb >= n) return;
    int nb = blockIdx.x * 64;
    const float* Bg = w2 + (size_t)e * HID * D + (size_t)c0 * D + nb;
    __shared__ short As[64 * 64];
    __shared__ short Bs[64 * 64];
    __shared__ int rowpid[64];
    int tid = threadIdx.x;
    int lane = tid & 63, wave = tid >> 6;
    int wr = wave >> 1, wc = wave & 1;
    if (tid < 64) {
        int r = mb + tid;
        rowpid[tid] = (r < n) ? list[e * T + r] : list[e * T];
    }
    __syncthreads();

    f32x4 acc[2][2] = {};
    int ar0 = tid >> 3, ak0 = (tid & 7) * 8;
    int ar1 = (tid + 256) >> 3, ak1 = ((tid + 256) & 7) * 8;
    int bn = (tid & 15) * 4, bk = (tid >> 4) * 4;
    const short* Asrc0 = g + (size_t)rowpid[ar0] * HC + ak0;
    const short* Asrc1 = g + (size_t)rowpid[ar1] * HC + ak1;

    bf16x8 a_c0 = *(const bf16x8*)(Asrc0);
    bf16x8 a_c1 = *(const bf16x8*)(Asrc1);
    float4 b_c[4];
#pragma unroll
    for (int i = 0; i < 4; i++) b_c[i] = *(const float4*)(Bg + (size_t)(bk + i) * D + bn);

    for (int k0 = 0; k0 < HC; k0 += 64) {
        bf16x8 a_n0, a_n1;
        float4 b_n[4];
        bool more = (k0 + 64) < HC;
        if (more) {
            a_n0 = *(const bf16x8*)(Asrc0 + k0 + 64);
            a_n1 = *(const bf16x8*)(Asrc1 + k0 + 64);
#pragma unroll
            for (int i = 0; i < 4; i++) b_n[i] = *(const float4*)(Bg + (size_t)(k0 + 64 + bk + i) * D + bn);
        }
        *(bf16x8*)&As[swzB(ar0, ak0)] = a_c0;
        *(bf16x8*)&As[swzB(ar1, ak1)] = a_c1;
        *(short4*)&Bs[swzB(bn + 0, bk)] = make_short4(f2bf(b_c[0].x), f2bf(b_c[1].x), f2bf(b_c[2].x), f2bf(b_c[3].x));
        *(short4*)&Bs[swzB(bn + 1, bk)] = make_short4(f2bf(b_c[0].y), f2bf(b_c[1].y), f2bf(b_c[2].y), f2bf(b_c[3].y));
        *(short4*)&Bs[swzB(bn + 2, bk)] = make_short4(f2bf(b_c[0].z), f2bf(b_c[1].z), f2bf(b_c[2].z), f2bf(b_c[3].z));
        *(short4*)&Bs[swzB(bn + 3, bk)] = make_short4(f2bf(b_c[0].w), f2bf(b_c[1].w), f2bf(b_c[2].w), f2bf(b_c[3].w));
        __syncthreads();
#pragma unroll
        for (int kk = 0; kk < 64; kk += 32) {
            int krd = kk + 8 * (lane >> 4);
            bf16x8 a0 = *(const bf16x8*)&As[swzB(wr * 32 + (lane & 15), krd)];
            bf16x8 a1 = *(const bf16x8*)&As[swzB(wr * 32 + 16 + (lane & 15), krd)];
            bf16x8 b0 = *(const bf16x8*)&Bs[swzB(wc * 32 + (lane & 15), krd)];
            bf16x8 b1 = *(const bf16x8*)&Bs[swzB(wc * 32 + 16 + (lane & 15), krd)];
            acc[0][0] = __builtin_amdgcn_mfma_f32_16x16x32_bf16(a0, b0, acc[0][0], 0, 0, 0);
            acc[0][1] = __builtin_amdgcn_mfma_f32_16x16x32_bf16(a0, b1, acc[0][1], 0, 0, 0);
            acc[1][0] = __builtin_amdgcn_mfma_f32_16x16x32_bf16(a1, b0, acc[1][0], 0, 0, 0);
            acc[1][1] = __builtin_amdgcn_mfma_f32_16x16x32_bf16(a1, b1, acc[1][1], 0, 0, 0);
        }
        __syncthreads();
        if (more) {
            a_c0 = a_n0; a_c1 = a_n1;
#pragma unroll
            for (int i = 0; i < 4; i++) b_c[i] = b_n[i];
        }
    }
#pragma unroll
    for (int mi = 0; mi < 2; mi++)
#pragma unroll
        for (int ni = 0; ni < 2; ni++)
#pragma unroll
            for (int r = 0; r < 4; r++) {
                int row = wr * 32 + mi * 16 + (lane >> 4) * 4 + r;
                if (mb + row < n) {
                    int pid = rowpid[row];
                    int col = nb + wc * 32 + ni * 16 + (lane & 15);
                    size_t o = (size_t)pid * D + col;
                    yp[o] = first ? acc[mi][ni][r] : (yp[o] + acc[mi][ni][r]);
                }
            }
}

// ---------------- final combine ----------------
__global__ void combine_kernel(const float* __restrict__ yp, const float* __restrict__ wtok,
                               float* __restrict__ out) {
    int idx = blockIdx.x * 256 + threadIdx.x; // T * (D/4)
    if (idx >= T * (D / 4)) return;
    int t = idx / (D / 4);
    int d4 = idx % (D / 4);
    float4 a = ((const float4*)(out + (size_t)t * D))[d4];
    float4 y0 = ((const float4*)(yp + (size_t)(2 * t) * D))[d4];
    float4 y1 = ((const float4*)(yp + (size_t)(2 * t + 1) * D))[d4];
    float w0 = wtok[2 * t], w1 = wtok[2 * t + 1];
    a.x += w0 * y0.x + w1 * y1.x;
    a.y += w0 * y0.y + w1 * y1.y;
    a.z += w0 * y0.z + w1 * y1.z;
    a.w += w0 * y0.w + w1 * y1.w;
    ((float4*)(out + (size_t)t * D))[d4] = a;
}

extern "C" void kernel_launch(void* const* d_in, const int* in_sizes, int n_in,
                              void* d_out, int out_size, void* d_ws, size_t ws_size,
                              hipStream_t stream) {
    const float* x    = (const float*)d_in[0];
    const float* n1w  = (const float*)d_in[1];
    const float* n2w  = (const float*)d_in[2];
    const float* wq   = (const float*)d_in[3];
    const float* wdkv = (const float*)d_in[4];
    const float* wuk  = (const float*)d_in[5];
    const float* wuv  = (const float*)d_in[6];
    const float* wo   = (const float*)d_in[7];
    const float* gw   = (const float*)d_in[8];
    const float* w1   = (const float*)d_in[9];
    const float* w2   = (const float*)d_in[10];
    const float* w3   = (const float*)d_in[11];
    const int*   sp   = (const int*)d_in[12];
    float* out = (float*)d_out;

    // ws layout (floats). Total ~17.1 MB (R1-proven footprint).
    float* ws = (float*)d_ws;
    float* A_  = ws + 0;                 // 786432: qb, later h2b
    float* B_  = ws + 786432;            // 786432: kb, later yp[0..]
    float* C_  = ws + 1572864;           // 786432: vb, later yp[..]
    float* Dd  = ws + 2359296;           // 786432: h, later ab
    float* cb  = ws + 3145728;           // 65536
    float* probs = ws + 3211264;         // 8192
    float* wtok  = ws + 3219456;         // 2048
    int*   list  = (int*)(ws + 3221504); // 8192 ints
    int*   counts= (int*)(ws + 3229696); // 16 ints
    short* gch   = (short*)(ws + 3229712); // 2T*HC bf16 = 4 MB
    float* yp = B_;                      // 2T*D fp32 (B_ and C_ contiguous)

    hipMemsetAsync(counts, 0, 16 * sizeof(int), stream);

    // ---- attention ----
    rmsnorm_kernel<<<T, 256, 0, stream>>>(x, n1w, Dd);                                       // h
    gemm_bf16<false><<<dim3(D / 64, T / 64), 256, 0, stream>>>(Dd, wq, nullptr, A_, T, D, D);    // qb
    gemm_bf16<false><<<dim3(1, T / 64), 256, 0, stream>>>(Dd, wdkv, nullptr, cb, T, DL, D);      // c
    gemm_kuv<<<dim3(D / 64, T / 64), 256, 0, stream>>>(cb, wuk, wuv, B_, C_, T, D, DL);          // kb, vb
    rope_kernel<<<(T * H * 32 + 255) / 256, 256, 0, stream>>>(A_, B_, sp);
    attn_mfma<<<dim3(8, H, BATCH), 256, 0, stream>>>(A_, B_, C_, Dd);                        // ab
    gemm_bf16<true><<<dim3(D / 64, T / 64), 256, 0, stream>>>(Dd, wo, x, out, T, D, D);      // x1 in out

    // ---- MoE ----
    rmsnorm_kernel<<<T, 256, 0, stream>>>(out, n2w, A_);                                     // h2
    routing_kernel<<<T, 64, 0, stream>>>(A_, gw, probs, list, counts, wtok);
    aux_kernel<<<1, 256, 0, stream>>>(probs, counts, out + (out_size - 1));
    for (int c0 = 0; c0 < HID; c0 += HC) {
        moe_up_mfma<<<dim3(HC / 64, T / 64, E), 256, 0, stream>>>(A_, w1, w3, list, counts, gch, c0);
        moe_down_mfma<<<dim3(D / 64, T / 64, E), 256, 0, stream>>>(gch, w2, list, counts, yp, c0, c0 == 0 ? 1 : 0);
    }
    combine_kernel<<<(T * (D / 4) + 255) / 256, 256, 0, stream>>>(yp, wtok, out);
}

// Round 10
// 305.808 us; speedup vs baseline: 4.8060x; 1.1945x over previous
//
#include <hip/hip_runtime.h>
#include <hip/hip_bf16.h>
#include <math.h>

#define T 1024
#define SEQ 512
#define BATCH 2
#define D 768
#define H 12
#define DH 64
#define DL 64
#define E 8
#define HID 3072

typedef __attribute__((ext_vector_type(8))) short bf16x8;
typedef __attribute__((ext_vector_type(4))) float f32x4;

// fp32 -> bf16 RNE via compiler (emits v_cvt_pk_bf16_f32 for pairs)
__device__ inline short f2bf(float f) {
    __hip_bfloat16 h = __float2bfloat16(f);
    return *reinterpret_cast<short*>(&h);
}

// attn swizzle (validated)
__device__ inline int swz(int row, int k) { return (row * 64 + k) ^ ((row & 7) << 3); }
// GEMM swizzle: XOR row bits 1..3 into k bits 3..5 (16B granules).
// Transpose-writes -> 4-way; fragment reads -> 2-way (free).
__device__ inline int swzB(int row, int k) { return row * 64 + (k ^ (((row >> 1) & 7) << 3)); }

// ---------------- rmsnorm ----------------
__global__ void rmsnorm_kernel(const float* __restrict__ x, const float* __restrict__ w,
                               float* __restrict__ out) {
    int t = blockIdx.x;
    int tid = threadIdx.x; // 256
    const float* xr = x + (size_t)t * D;
    float s = 0.f;
    for (int i = tid; i < D; i += 256) { float v = xr[i]; s += v * v; }
    __shared__ float red[256];
    red[tid] = s; __syncthreads();
    for (int o = 128; o > 0; o >>= 1) { if (tid < o) red[tid] += red[tid + o]; __syncthreads(); }
    float scale = 1.0f / sqrtf(red[0] / (float)D + 1e-6f);
    for (int i = tid; i < D; i += 256) out[(size_t)t * D + i] = xr[i] * scale * w[i];
}

// ---------------- dense bf16 MFMA GEMM: C = A@B (+R). 64|M,N,K ----------------
template<bool RES>
__global__ __launch_bounds__(256) void gemm_bf16(
    const float* __restrict__ A, const float* __restrict__ B,
    const float* __restrict__ Rp, float* __restrict__ C,
    int M, int N, int K) {
    int mb = blockIdx.y * 64, nb = blockIdx.x * 64;
    __shared__ short As[64 * 64];
    __shared__ short Bs[64 * 64];
    int tid = threadIdx.x;
    int lane = tid & 63, wave = tid >> 6;
    int wr = wave >> 1, wc = wave & 1;
    f32x4 acc[2][2] = {};
    int ar = tid >> 2, ac = (tid & 3) * 16;
    int bn = (tid & 15) * 4, bk = (tid >> 4) * 4;
    const float* Arow = A + (size_t)(mb + ar) * K + ac;
    const float* Bg = B + nb;
    float4 a_c[4], b_c[4];
#pragma unroll
    for (int j = 0; j < 4; j++) a_c[j] = *(const float4*)(Arow + j * 4);
#pragma unroll
    for (int i = 0; i < 4; i++) b_c[i] = *(const float4*)(Bg + (size_t)(bk + i) * N + bn);
    for (int k0 = 0; k0 < K; k0 += 64) {
        float4 a_n[4], b_n[4];
        bool more = (k0 + 64) < K;
        if (more) {
#pragma unroll
            for (int j = 0; j < 4; j++) a_n[j] = *(const float4*)(Arow + k0 + 64 + j * 4);
#pragma unroll
            for (int i = 0; i < 4; i++) b_n[i] = *(const float4*)(Bg + (size_t)(k0 + 64 + bk + i) * N + bn);
        }
#pragma unroll
        for (int j = 0; j < 4; j++)
            *(short4*)&As[swzB(ar, ac + j * 4)] =
                make_short4(f2bf(a_c[j].x), f2bf(a_c[j].y), f2bf(a_c[j].z), f2bf(a_c[j].w));
        *(short4*)&Bs[swzB(bn + 0, bk)] = make_short4(f2bf(b_c[0].x), f2bf(b_c[1].x), f2bf(b_c[2].x), f2bf(b_c[3].x));
        *(short4*)&Bs[swzB(bn + 1, bk)] = make_short4(f2bf(b_c[0].y), f2bf(b_c[1].y), f2bf(b_c[2].y), f2bf(b_c[3].y));
        *(short4*)&Bs[swzB(bn + 2, bk)] = make_short4(f2bf(b_c[0].z), f2bf(b_c[1].z), f2bf(b_c[2].z), f2bf(b_c[3].z));
        *(short4*)&Bs[swzB(bn + 3, bk)] = make_short4(f2bf(b_c[0].w), f2bf(b_c[1].w), f2bf(b_c[2].w), f2bf(b_c[3].w));
        __syncthreads();
#pragma unroll
        for (int kk = 0; kk < 64; kk += 32) {
            int krd = kk + 8 * (lane >> 4);
            bf16x8 a0 = *(const bf16x8*)&As[swzB(wr * 32 + (lane & 15), krd)];
            bf16x8 a1 = *(const bf16x8*)&As[swzB(wr * 32 + 16 + (lane & 15), krd)];
            bf16x8 b0 = *(const bf16x8*)&Bs[swzB(wc * 32 + (lane & 15), krd)];
            bf16x8 b1 = *(const bf16x8*)&Bs[swzB(wc * 32 + 16 + (lane & 15), krd)];
            acc[0][0] = __builtin_amdgcn_mfma_f32_16x16x32_bf16(a0, b0, acc[0][0], 0, 0, 0);
            acc[0][1] = __builtin_amdgcn_mfma_f32_16x16x32_bf16(a0, b1, acc[0][1], 0, 0, 0);
            acc[1][0] = __builtin_amdgcn_mfma_f32_16x16x32_bf16(a1, b0, acc[1][0], 0, 0, 0);
            acc[1][1] = __builtin_amdgcn_mfma_f32_16x16x32_bf16(a1, b1, acc[1][1], 0, 0, 0);
        }
        __syncthreads();
        if (more) {
#pragma unroll
            for (int j = 0; j < 4; j++) { a_c[j] = a_n[j]; b_c[j] = b_n[j]; }
        }
    }
#pragma unroll
    for (int mi = 0; mi < 2; mi++)
#pragma unroll
        for (int ni = 0; ni < 2; ni++)
#pragma unroll
            for (int r = 0; r < 4; r++) {
                int row = mb + wr * 32 + mi * 16 + (lane >> 4) * 4 + r;
                int col = nb + wc * 32 + ni * 16 + (lane & 15);
                float val = acc[mi][ni][r];
                if (RES) val += Rp[(size_t)row * N + col];
                C[(size_t)row * N + col] = val;
            }
}

// ---- fused K/V up-projection: kb = cb@wuk, vb = cb@wuv (K=DL=64, single K-step) ----
__global__ __launch_bounds__(256) void gemm_kuv(
    const float* __restrict__ A, const float* __restrict__ Bk, const float* __restrict__ Bv,
    float* __restrict__ Ck, float* __restrict__ Cv, int M, int N, int K) {
    int mb = blockIdx.y * 64, nb = blockIdx.x * 64;
    __shared__ short As[64 * 64];
    __shared__ short B1s[64 * 64];
    __shared__ short B2s[64 * 64];
    int tid = threadIdx.x;
    int lane = tid & 63, wave = tid >> 6;
    int wr = wave >> 1, wc = wave & 1;
    f32x4 acc1[2][2] = {};
    f32x4 acc2[2][2] = {};
    int ar = tid >> 2, ac = (tid & 3) * 16;
    int bn = (tid & 15) * 4, bk = (tid >> 4) * 4;
    const float* Arow = A + (size_t)(mb + ar) * K + ac;
    {
        float4 a_c[4], p_c[4], q_c[4];
#pragma unroll
        for (int j = 0; j < 4; j++) a_c[j] = *(const float4*)(Arow + j * 4);
#pragma unroll
        for (int i = 0; i < 4; i++) {
            p_c[i] = *(const float4*)(Bk + (size_t)(bk + i) * N + nb + bn);
            q_c[i] = *(const float4*)(Bv + (size_t)(bk + i) * N + nb + bn);
        }
#pragma unroll
        for (int j = 0; j < 4; j++)
            *(short4*)&As[swzB(ar, ac + j * 4)] =
                make_short4(f2bf(a_c[j].x), f2bf(a_c[j].y), f2bf(a_c[j].z), f2bf(a_c[j].w));
        *(short4*)&B1s[swzB(bn + 0, bk)] = make_short4(f2bf(p_c[0].x), f2bf(p_c[1].x), f2bf(p_c[2].x), f2bf(p_c[3].x));
        *(short4*)&B1s[swzB(bn + 1, bk)] = make_short4(f2bf(p_c[0].y), f2bf(p_c[1].y), f2bf(p_c[2].y), f2bf(p_c[3].y));
        *(short4*)&B1s[swzB(bn + 2, bk)] = make_short4(f2bf(p_c[0].z), f2bf(p_c[1].z), f2bf(p_c[2].z), f2bf(p_c[3].z));
        *(short4*)&B1s[swzB(bn + 3, bk)] = make_short4(f2bf(p_c[0].w), f2bf(p_c[1].w), f2bf(p_c[2].w), f2bf(p_c[3].w));
        *(short4*)&B2s[swzB(bn + 0, bk)] = make_short4(f2bf(q_c[0].x), f2bf(q_c[1].x), f2bf(q_c[2].x), f2bf(q_c[3].x));
        *(short4*)&B2s[swzB(bn + 1, bk)] = make_short4(f2bf(q_c[0].y), f2bf(q_c[1].y), f2bf(q_c[2].y), f2bf(q_c[3].y));
        *(short4*)&B2s[swzB(bn + 2, bk)] = make_short4(f2bf(q_c[0].z), f2bf(q_c[1].z), f2bf(q_c[2].z), f2bf(q_c[3].z));
        *(short4*)&B2s[swzB(bn + 3, bk)] = make_short4(f2bf(q_c[0].w), f2bf(q_c[1].w), f2bf(q_c[2].w), f2bf(q_c[3].w));
    }
    __syncthreads();
#pragma unroll
    for (int kk = 0; kk < 64; kk += 32) {
        int krd = kk + 8 * (lane >> 4);
        bf16x8 a0 = *(const bf16x8*)&As[swzB(wr * 32 + (lane & 15), krd)];
        bf16x8 a1 = *(const bf16x8*)&As[swzB(wr * 32 + 16 + (lane & 15), krd)];
        bf16x8 p0 = *(const bf16x8*)&B1s[swzB(wc * 32 + (lane & 15), krd)];
        bf16x8 p1 = *(const bf16x8*)&B1s[swzB(wc * 32 + 16 + (lane & 15), krd)];
        bf16x8 q0 = *(const bf16x8*)&B2s[swzB(wc * 32 + (lane & 15), krd)];
        bf16x8 q1 = *(const bf16x8*)&B2s[swzB(wc * 32 + 16 + (lane & 15), krd)];
        acc1[0][0] = __builtin_amdgcn_mfma_f32_16x16x32_bf16(a0, p0, acc1[0][0], 0, 0, 0);
        acc1[0][1] = __builtin_amdgcn_mfma_f32_16x16x32_bf16(a0, p1, acc1[0][1], 0, 0, 0);
        acc1[1][0] = __builtin_amdgcn_mfma_f32_16x16x32_bf16(a1, p0, acc1[1][0], 0, 0, 0);
        acc1[1][1] = __builtin_amdgcn_mfma_f32_16x16x32_bf16(a1, p1, acc1[1][1], 0, 0, 0);
        acc2[0][0] = __builtin_amdgcn_mfma_f32_16x16x32_bf16(a0, q0, acc2[0][0], 0, 0, 0);
        acc2[0][1] = __builtin_amdgcn_mfma_f32_16x16x32_bf16(a0, q1, acc2[0][1], 0, 0, 0);
        acc2[1][0] = __builtin_amdgcn_mfma_f32_16x16x32_bf16(a1, q0, acc2[1][0], 0, 0, 0);
        acc2[1][1] = __builtin_amdgcn_mfma_f32_16x16x32_bf16(a1, q1, acc2[1][1], 0, 0, 0);
    }
#pragma unroll
    for (int mi = 0; mi < 2; mi++)
#pragma unroll
        for (int ni = 0; ni < 2; ni++)
#pragma unroll
            for (int r = 0; r < 4; r++) {
                int row = mb + wr * 32 + mi * 16 + (lane >> 4) * 4 + r;
                int col = nb + wc * 32 + ni * 16 + (lane & 15);
                Ck[(size_t)row * N + col] = acc1[mi][ni][r];
                Cv[(size_t)row * N + col] = acc2[mi][ni][r];
            }
}

// ---------------- RoPE (in-place on q and k) ----------------
__global__ void rope_kernel(float* __restrict__ qb, float* __restrict__ kb,
                            const int* __restrict__ spp) {
    int p = blockIdx.x * 256 + threadIdx.x; // T*H*32
    if (p >= T * H * 32) return;
    int i = p & 31;
    int rem = p >> 5;
    int h = rem % H;
    int ts = rem / H;
    int s = ts % SEQ;
    float invf = powf(10000.0f, -(float)(2 * i) / 64.0f);
    float ang = (float)(s + spp[0]) * invf;
    float c = cosf(ang), sn = sinf(ang);
    size_t base = (size_t)ts * D + h * DH;
    float x1 = qb[base + i], x2 = qb[base + 32 + i];
    qb[base + i] = x1 * c - x2 * sn;
    qb[base + 32 + i] = x1 * sn + x2 * c;
    x1 = kb[base + i]; x2 = kb[base + 32 + i];
    kb[base + i] = x1 * c - x2 * sn;
    kb[base + 32 + i] = x1 * sn + x2 * c;
}

// ---------------- flash attention, MFMA bf16 (unchanged) ----------------
__global__ __launch_bounds__(256) void attn_mfma(
    const float* __restrict__ q, const float* __restrict__ k,
    const float* __restrict__ v, float* __restrict__ a) {
    int qt = blockIdx.x, h = blockIdx.y, b = blockIdx.z;
    int tid = threadIdx.x, lane = tid & 63, wave = tid >> 6;
    __shared__ short Qs[64 * 64];
    __shared__ short Ks[64 * 64];
    __shared__ short Vs[64 * 64];
    __shared__ short Ps[64 * 64];
    int qbase = qt * 64;
    {
        int r = tid >> 2, d0 = (tid & 3) * 16;
        const float* src = q + ((size_t)(b * SEQ + qbase + r)) * D + h * DH + d0;
#pragma unroll
        for (int j = 0; j < 4; j++) {
            float4 vv = *(const float4*)(src + j * 4);
            *(short4*)&Qs[swz(r, d0 + j * 4)] =
                make_short4(f2bf(vv.x), f2bf(vv.y), f2bf(vv.z), f2bf(vv.w));
        }
    }
    __syncthreads();
    bf16x8 qf0 = *(const bf16x8*)&Qs[swz(wave * 16 + (lane & 15), 8 * (lane >> 4))];
    bf16x8 qf1 = *(const bf16x8*)&Qs[swz(wave * 16 + (lane & 15), 32 + 8 * (lane >> 4))];

    float m_run[4] = {-1e30f, -1e30f, -1e30f, -1e30f};
    float l_run[4] = {0.f, 0.f, 0.f, 0.f};
    f32x4 o[4] = {};

    for (int kt = 0; kt <= qt; kt++) {
        int kvbase = kt * 64;
        {
            int r = tid >> 2, d0 = (tid & 3) * 16;
            const float* src = k + ((size_t)(b * SEQ + kvbase + r)) * D + h * DH + d0;
#pragma unroll
            for (int j = 0; j < 4; j++) {
                float4 vv = *(const float4*)(src + j * 4);
                *(short4*)&Ks[swz(r, d0 + j * 4)] =
                    make_short4(f2bf(vv.x), f2bf(vv.y), f2bf(vv.z), f2bf(vv.w));
            }
        }
#pragma unroll
        for (int i = 0; i < 4; i++) {
            int idx = tid + i * 256;
            int kr = idx >> 4, d0 = (idx & 15) * 4;
            float4 vv = *(const float4*)(v + ((size_t)(b * SEQ + kvbase + kr)) * D + h * DH + d0);
            Vs[swz(d0 + 0, kr)] = f2bf(vv.x); Vs[swz(d0 + 1, kr)] = f2bf(vv.y);
            Vs[swz(d0 + 2, kr)] = f2bf(vv.z); Vs[swz(d0 + 3, kr)] = f2bf(vv.w);
        }
        __syncthreads();

        f32x4 s[4];
#pragma unroll
        for (int kvt = 0; kvt < 4; kvt++) {
            bf16x8 kf0 = *(const bf16x8*)&Ks[swz(kvt * 16 + (lane & 15), 8 * (lane >> 4))];
            bf16x8 kf1 = *(const bf16x8*)&Ks[swz(kvt * 16 + (lane & 15), 32 + 8 * (lane >> 4))];
            f32x4 z = {};
            z = __builtin_amdgcn_mfma_f32_16x16x32_bf16(qf0, kf0, z, 0, 0, 0);
            z = __builtin_amdgcn_mfma_f32_16x16x32_bf16(qf1, kf1, z, 0, 0, 0);
            s[kvt] = z;
        }
#pragma unroll
        for (int kvt = 0; kvt < 4; kvt++) {
#pragma unroll
            for (int r = 0; r < 4; r++) {
                float val = s[kvt][r] * 0.125f;
                if (kt == qt) {
                    int kv_abs = kvbase + kvt * 16 + (lane & 15);
                    int q_abs = qbase + wave * 16 + (lane >> 4) * 4 + r;
                    if (kv_abs > q_abs) val = -1e30f;
                }
                s[kvt][r] = val;
            }
        }
        float mnew[4], psum[4], scl[4];
#pragma unroll
        for (int r = 0; r < 4; r++) {
            float mx = fmaxf(fmaxf(s[0][r], s[1][r]), fmaxf(s[2][r], s[3][r]));
#pragma unroll
            for (int o2 = 8; o2 > 0; o2 >>= 1) mx = fmaxf(mx, __shfl_xor(mx, o2));
            mnew[r] = fmaxf(m_run[r], mx);
            float ps = 0.f;
#pragma unroll
            for (int kvt = 0; kvt < 4; kvt++) {
                float p = expf(s[kvt][r] - mnew[r]);
                s[kvt][r] = p;
                ps += p;
            }
#pragma unroll
            for (int o2 = 8; o2 > 0; o2 >>= 1) ps += __shfl_xor(ps, o2);
            psum[r] = ps;
            scl[r] = expf(m_run[r] - mnew[r]);
            m_run[r] = mnew[r];
            l_run[r] = l_run[r] * scl[r] + psum[r];
        }
#pragma unroll
        for (int dt = 0; dt < 4; dt++)
#pragma unroll
            for (int r = 0; r < 4; r++) o[dt][r] *= scl[r];
#pragma unroll
        for (int kvt = 0; kvt < 4; kvt++)
#pragma unroll
            for (int r = 0; r < 4; r++)
                Ps[swz(wave * 16 + (lane >> 4) * 4 + r, kvt * 16 + (lane & 15))] = f2bf(s[kvt][r]);
        __syncthreads();
        bf16x8 pa0 = *(const bf16x8*)&Ps[swz(wave * 16 + (lane & 15), 8 * (lane >> 4))];
        bf16x8 pa1 = *(const bf16x8*)&Ps[swz(wave * 16 + (lane & 15), 32 + 8 * (lane >> 4))];
#pragma unroll
        for (int dt = 0; dt < 4; dt++) {
            bf16x8 vf0 = *(const bf16x8*)&Vs[swz(dt * 16 + (lane & 15), 8 * (lane >> 4))];
            bf16x8 vf1 = *(const bf16x8*)&Vs[swz(dt * 16 + (lane & 15), 32 + 8 * (lane >> 4))];
            o[dt] = __builtin_amdgcn_mfma_f32_16x16x32_bf16(pa0, vf0, o[dt], 0, 0, 0);
            o[dt] = __builtin_amdgcn_mfma_f32_16x16x32_bf16(pa1, vf1, o[dt], 0, 0, 0);
        }
        __syncthreads();
    }
#pragma unroll
    for (int r = 0; r < 4; r++) {
        float inv = 1.0f / l_run[r];
        int qrow = qbase + wave * 16 + (lane >> 4) * 4 + r;
#pragma unroll
        for (int dt = 0; dt < 4; dt++) {
            a[((size_t)(b * SEQ + qrow)) * D + h * DH + dt * 16 + (lane & 15)] = o[dt][r] * inv;
        }
    }
}

// ---------------- routing ----------------
__global__ void routing_kernel(const float* __restrict__ h2, const float* __restrict__ gw,
                               float* __restrict__ probs, int* __restrict__ list,
                               int* __restrict__ counts, float* __restrict__ wtok) {
    int t = blockIdx.x;
    int tid = threadIdx.x; // 64
    __shared__ float part[64][8];
    float l[8] = {0.f, 0.f, 0.f, 0.f, 0.f, 0.f, 0.f, 0.f};
    const float* hr = h2 + (size_t)t * D;
    for (int i = tid; i < D; i += 64) {
        float hv = hr[i];
        const float* g = gw + (size_t)i * E;
#pragma unroll
        for (int e = 0; e < 8; e++) l[e] += hv * g[e];
    }
#pragma unroll
    for (int e = 0; e < 8; e++) part[tid][e] = l[e];
    __syncthreads();
    if (tid == 0) {
        float lg[8];
#pragma unroll
        for (int e = 0; e < 8; e++) {
            float s = 0.f;
            for (int j = 0; j < 64; j++) s += part[j][e];
            lg[e] = s;
        }
        float m = lg[0];
#pragma unroll
        for (int e = 1; e < 8; e++) m = fmaxf(m, lg[e]);
        float se = 0.f;
        float pr[8];
#pragma unroll
        for (int e = 0; e < 8; e++) { pr[e] = expf(lg[e] - m); se += pr[e]; }
#pragma unroll
        for (int e = 0; e < 8; e++) { pr[e] /= se; probs[t * 8 + e] = pr[e]; }
        int i0 = 0;
#pragma unroll
        for (int e = 1; e < 8; e++) if (pr[e] > pr[i0]) i0 = e;
        int i1 = -1;
#pragma unroll
        for (int e = 0; e < 8; e++) {
            if (e == i0) continue;
            if (i1 < 0 || pr[e] > pr[i1]) i1 = e;
        }
        float w0 = pr[i0], w1 = pr[i1];
        float wsum = w0 + w1;
        wtok[t * 2 + 0] = w0 / wsum;
        wtok[t * 2 + 1] = w1 / wsum;
        int p0 = atomicAdd(&counts[i0], 1); list[i0 * T + p0] = t * 2 + 0;
        int p1 = atomicAdd(&counts[i1], 1); list[i1 * T + p1] = t * 2 + 1;
    }
}

// ---------------- aux loss ----------------
__global__ void aux_kernel(const float* __restrict__ probs, const int* __restrict__ counts,
                           float* __restrict__ out_aux) {
    int tid = threadIdx.x;
    __shared__ float ps[8];
    if (tid < 8) {
        float s = 0.f;
        for (int t = 0; t < T; t++) s += probs[t * 8 + tid];
        ps[tid] = s;
    }
    __syncthreads();
    if (tid == 0) {
        float aux = 0.f;
        for (int e = 0; e < 8; e++) {
            float f = (float)counts[e] / (float)T;
            float P = ps[e] / (float)T;
            aux += f * P;
        }
        out_aux[0] = (float)E * aux;
    }
}

// ---- MoE up, MFMA bf16, reg-transpose staging + prefetch; hc/c0 runtime ----
__global__ __launch_bounds__(256) void moe_up_mfma(
    const float* __restrict__ h2, const float* __restrict__ w1, const float* __restrict__ w3,
    const int* __restrict__ list, const int* __restrict__ counts,
    short* __restrict__ g, int hc, int c0) {
    int e = blockIdx.z;
    int n = counts[e];
    int mb = blockIdx.y * 64;
    if (mb >= n) return;
    int nb = blockIdx.x * 64;  // col within chunk
    const float* B1g = w1 + (size_t)e * D * HID + (c0 + nb);
    const float* B3g = w3 + (size_t)e * D * HID + (c0 + nb);
    __shared__ short As[64 * 64];
    __shared__ short B1s[64 * 64];
    __shared__ short B3s[64 * 64];
    __shared__ int rowpid[64];
    __shared__ int rowtok[64];
    int tid = threadIdx.x;
    int lane = tid & 63, wave = tid >> 6;
    int wr = wave >> 1, wc = wave & 1;
    if (tid < 64) {
        int r = mb + tid;
        int pid = (r < n) ? list[e * T + r] : list[e * T];
        rowpid[tid] = pid;
        rowtok[tid] = pid >> 1;
    }
    __syncthreads();

    f32x4 acc1[2][2] = {};
    f32x4 acc3[2][2] = {};
    int ar = tid >> 2, ac = (tid & 3) * 16;
    int bn = (tid & 15) * 4, bk = (tid >> 4) * 4;
    const float* Arow = h2 + (size_t)rowtok[ar] * D + ac;

    float4 a_c[4], b1_c[4], b3_c[4];
#pragma unroll
    for (int j = 0; j < 4; j++) a_c[j] = *(const float4*)(Arow + j * 4);
#pragma unroll
    for (int i = 0; i < 4; i++) {
        b1_c[i] = *(const float4*)(B1g + (size_t)(bk + i) * HID + bn);
        b3_c[i] = *(const float4*)(B3g + (size_t)(bk + i) * HID + bn);
    }
    for (int k0 = 0; k0 < D; k0 += 64) {
        float4 a_n[4], b1_n[4], b3_n[4];
        bool more = (k0 + 64) < D;
        if (more) {
#pragma unroll
            for (int j = 0; j < 4; j++) a_n[j] = *(const float4*)(Arow + k0 + 64 + j * 4);
#pragma unroll
            for (int i = 0; i < 4; i++) {
                b1_n[i] = *(const float4*)(B1g + (size_t)(k0 + 64 + bk + i) * HID + bn);
                b3_n[i] = *(const float4*)(B3g + (size_t)(k0 + 64 + bk + i) * HID + bn);
            }
        }
#pragma unroll
        for (int j = 0; j < 4; j++)
            *(short4*)&As[swzB(ar, ac + j * 4)] =
                make_short4(f2bf(a_c[j].x), f2bf(a_c[j].y), f2bf(a_c[j].z), f2bf(a_c[j].w));
        *(short4*)&B1s[swzB(bn + 0, bk)] = make_short4(f2bf(b1_c[0].x), f2bf(b1_c[1].x), f2bf(b1_c[2].x), f2bf(b1_c[3].x));
        *(short4*)&B1s[swzB(bn + 1, bk)] = make_short4(f2bf(b1_c[0].y), f2bf(b1_c[1].y), f2bf(b1_c[2].y), f2bf(b1_c[3].y));
        *(short4*)&B1s[swzB(bn + 2, bk)] = make_short4(f2bf(b1_c[0].z), f2bf(b1_c[1].z), f2bf(b1_c[2].z), f2bf(b1_c[3].z));
        *(short4*)&B1s[swzB(bn + 3, bk)] = make_short4(f2bf(b1_c[0].w), f2bf(b1_c[1].w), f2bf(b1_c[2].w), f2bf(b1_c[3].w));
        *(short4*)&B3s[swzB(bn + 0, bk)] = make_short4(f2bf(b3_c[0].x), f2bf(b3_c[1].x), f2bf(b3_c[2].x), f2bf(b3_c[3].x));
        *(short4*)&B3s[swzB(bn + 1, bk)] = make_short4(f2bf(b3_c[0].y), f2bf(b3_c[1].y), f2bf(b3_c[2].y), f2bf(b3_c[3].y));
        *(short4*)&B3s[swzB(bn + 2, bk)] = make_short4(f2bf(b3_c[0].z), f2bf(b3_c[1].z), f2bf(b3_c[2].z), f2bf(b3_c[3].z));
        *(short4*)&B3s[swzB(bn + 3, bk)] = make_short4(f2bf(b3_c[0].w), f2bf(b3_c[1].w), f2bf(b3_c[2].w), f2bf(b3_c[3].w));
        __syncthreads();
#pragma unroll
        for (int kk = 0; kk < 64; kk += 32) {
            int krd = kk + 8 * (lane >> 4);
            bf16x8 a0  = *(const bf16x8*)&As[swzB(wr * 32 + (lane & 15), krd)];
            bf16x8 a1  = *(const bf16x8*)&As[swzB(wr * 32 + 16 + (lane & 15), krd)];
            bf16x8 b10 = *(const bf16x8*)&B1s[swzB(wc * 32 + (lane & 15), krd)];
            bf16x8 b11 = *(const bf16x8*)&B1s[swzB(wc * 32 + 16 + (lane & 15), krd)];
            bf16x8 b30 = *(const bf16x8*)&B3s[swzB(wc * 32 + (lane & 15), krd)];
            bf16x8 b31 = *(const bf16x8*)&B3s[swzB(wc * 32 + 16 + (lane & 15), krd)];
            acc1[0][0] = __builtin_amdgcn_mfma_f32_16x16x32_bf16(a0, b10, acc1[0][0], 0, 0, 0);
            acc1[0][1] = __builtin_amdgcn_mfma_f32_16x16x32_bf16(a0, b11, acc1[0][1], 0, 0, 0);
            acc1[1][0] = __builtin_amdgcn_mfma_f32_16x16x32_bf16(a1, b10, acc1[1][0], 0, 0, 0);
            acc1[1][1] = __builtin_amdgcn_mfma_f32_16x16x32_bf16(a1, b11, acc1[1][1], 0, 0, 0);
            acc3[0][0] = __builtin_amdgcn_mfma_f32_16x16x32_bf16(a0, b30, acc3[0][0], 0, 0, 0);
            acc3[0][1] = __builtin_amdgcn_mfma_f32_16x16x32_bf16(a0, b31, acc3[0][1], 0, 0, 0);
            acc3[1][0] = __builtin_amdgcn_mfma_f32_16x16x32_bf16(a1, b30, acc3[1][0], 0, 0, 0);
            acc3[1][1] = __builtin_amdgcn_mfma_f32_16x16x32_bf16(a1, b31, acc3[1][1], 0, 0, 0);
        }
        __syncthreads();
        if (more) {
#pragma unroll
            for (int j = 0; j < 4; j++) { a_c[j] = a_n[j]; b1_c[j] = b1_n[j]; b3_c[j] = b3_n[j]; }
        }
    }
#pragma unroll
    for (int mi = 0; mi < 2; mi++)
#pragma unroll
        for (int ni = 0; ni < 2; ni++)
#pragma unroll
            for (int r = 0; r < 4; r++) {
                int row = wr * 32 + mi * 16 + (lane >> 4) * 4 + r;
                if (mb + row < n) {
                    int pid = rowpid[row];
                    int col = nb + wc * 32 + ni * 16 + (lane & 15);
                    float v1 = acc1[mi][ni][r], v3 = acc3[mi][ni][r];
                    float sil = v1 / (1.f + expf(-v1));
                    g[(size_t)pid * hc + col] = f2bf(sil * v3);
                }
            }
}

// ---- MoE down, MFMA bf16, reg-transpose staging + prefetch; hc/c0 runtime ----
__global__ __launch_bounds__(256) void moe_down_mfma(
    const short* __restrict__ g, const float* __restrict__ w2,
    const int* __restrict__ list, const int* __restrict__ counts,
    float* __restrict__ yp, int hc, int c0, int first) {
    int e = blockIdx.z;
    int n = counts[e];
    int mb = blockIdx.y * 64;
    if (mb >= n) return;
    int nb = blockIdx.x * 64;
    const float* Bg = w2 + (size_t)e * HID * D + (size_t)c0 * D + nb;
    __shared__ short As[64 * 64];
    __shared__ short Bs[64 * 64];
    __shared__ int rowpid[64];
    int tid = threadIdx.x;
    int lane = tid & 63, wave = tid >> 6;
    int wr = wave >> 1, wc = wave & 1;
    if (tid < 64) {
        int r = mb + tid;
        rowpid[tid] = (r < n) ? list[e * T + r] : list[e * T];
    }
    __syncthreads();

    f32x4 acc[2][2] = {};
    int ar0 = tid >> 3, ak0 = (tid & 7) * 8;
    int ar1 = (tid + 256) >> 3, ak1 = ((tid + 256) & 7) * 8;
    int bn = (tid & 15) * 4, bk = (tid >> 4) * 4;
    const short* Asrc0 = g + (size_t)rowpid[ar0] * hc + ak0;
    const short* Asrc1 = g + (size_t)rowpid[ar1] * hc + ak1;

    bf16x8 a_c0 = *(const bf16x8*)(Asrc0);
    bf16x8 a_c1 = *(const bf16x8*)(Asrc1);
    float4 b_c[4];
#pragma unroll
    for (int i = 0; i < 4; i++) b_c[i] = *(const float4*)(Bg + (size_t)(bk + i) * D + bn);

    for (int k0 = 0; k0 < hc; k0 += 64) {
        bf16x8 a_n0, a_n1;
        float4 b_n[4];
        bool more = (k0 + 64) < hc;
        if (more) {
            a_n0 = *(const bf16x8*)(Asrc0 + k0 + 64);
            a_n1 = *(const bf16x8*)(Asrc1 + k0 + 64);
#pragma unroll
            for (int i = 0; i < 4; i++) b_n[i] = *(const float4*)(Bg + (size_t)(k0 + 64 + bk + i) * D + bn);
        }
        *(bf16x8*)&As[swzB(ar0, ak0)] = a_c0;
        *(bf16x8*)&As[swzB(ar1, ak1)] = a_c1;
        *(short4*)&Bs[swzB(bn + 0, bk)] = make_short4(f2bf(b_c[0].x), f2bf(b_c[1].x), f2bf(b_c[2].x), f2bf(b_c[3].x));
        *(short4*)&Bs[swzB(bn + 1, bk)] = make_short4(f2bf(b_c[0].y), f2bf(b_c[1].y), f2bf(b_c[2].y), f2bf(b_c[3].y));
        *(short4*)&Bs[swzB(bn + 2, bk)] = make_short4(f2bf(b_c[0].z), f2bf(b_c[1].z), f2bf(b_c[2].z), f2bf(b_c[3].z));
        *(short4*)&Bs[swzB(bn + 3, bk)] = make_short4(f2bf(b_c[0].w), f2bf(b_c[1].w), f2bf(b_c[2].w), f2bf(b_c[3].w));
        __syncthreads();
#pragma unroll
        for (int kk = 0; kk < 64; kk += 32) {
            int krd = kk + 8 * (lane >> 4);
            bf16x8 a0 = *(const bf16x8*)&As[swzB(wr * 32 + (lane & 15), krd)];
            bf16x8 a1 = *(const bf16x8*)&As[swzB(wr * 32 + 16 + (lane & 15), krd)];
            bf16x8 b0 = *(const bf16x8*)&Bs[swzB(wc * 32 + (lane & 15), krd)];
            bf16x8 b1 = *(const bf16x8*)&Bs[swzB(wc * 32 + 16 + (lane & 15), krd)];
            acc[0][0] = __builtin_amdgcn_mfma_f32_16x16x32_bf16(a0, b0, acc[0][0], 0, 0, 0);
            acc[0][1] = __builtin_amdgcn_mfma_f32_16x16x32_bf16(a0, b1, acc[0][1], 0, 0, 0);
            acc[1][0] = __builtin_amdgcn_mfma_f32_16x16x32_bf16(a1, b0, acc[1][0], 0, 0, 0);
            acc[1][1] = __builtin_amdgcn_mfma_f32_16x16x32_bf16(a1, b1, acc[1][1], 0, 0, 0);
        }
        __syncthreads();
        if (more) {
            a_c0 = a_n0; a_c1 = a_n1;
#pragma unroll
            for (int i = 0; i < 4; i++) b_c[i] = b_n[i];
        }
    }
#pragma unroll
    for (int mi = 0; mi < 2; mi++)
#pragma unroll
        for (int ni = 0; ni < 2; ni++)
#pragma unroll
            for (int r = 0; r < 4; r++) {
                int row = wr * 32 + mi * 16 + (lane >> 4) * 4 + r;
                if (mb + row < n) {
                    int pid = rowpid[row];
                    int col = nb + wc * 32 + ni * 16 + (lane & 15);
                    size_t o = (size_t)pid * D + col;
                    yp[o] = first ? acc[mi][ni][r] : (yp[o] + acc[mi][ni][r]);
                }
            }
}

// ---------------- final combine ----------------
__global__ void combine_kernel(const float* __restrict__ yp, const float* __restrict__ wtok,
                               float* __restrict__ out) {
    int idx = blockIdx.x * 256 + threadIdx.x; // T * (D/4)
    if (idx >= T * (D / 4)) return;
    int t = idx / (D / 4);
    int d4 = idx % (D / 4);
    float4 a = ((const float4*)(out + (size_t)t * D))[d4];
    float4 y0 = ((const float4*)(yp + (size_t)(2 * t) * D))[d4];
    float4 y1 = ((const float4*)(yp + (size_t)(2 * t + 1) * D))[d4];
    float w0 = wtok[2 * t], w1 = wtok[2 * t + 1];
    a.x += w0 * y0.x + w1 * y1.x;
    a.y += w0 * y0.y + w1 * y1.y;
    a.z += w0 * y0.z + w1 * y1.z;
    a.w += w0 * y0.w + w1 * y1.w;
    ((float4*)(out + (size_t)t * D))[d4] = a;
}

extern "C" void kernel_launch(void* const* d_in, const int* in_sizes, int n_in,
                              void* d_out, int out_size, void* d_ws, size_t ws_size,
                              hipStream_t stream) {
    const float* x    = (const float*)d_in[0];
    const float* n1w  = (const float*)d_in[1];
    const float* n2w  = (const float*)d_in[2];
    const float* wq   = (const float*)d_in[3];
    const float* wdkv = (const float*)d_in[4];
    const float* wuk  = (const float*)d_in[5];
    const float* wuv  = (const float*)d_in[6];
    const float* wo   = (const float*)d_in[7];
    const float* gw   = (const float*)d_in[8];
    const float* w1   = (const float*)d_in[9];
    const float* w2   = (const float*)d_in[10];
    const float* w3   = (const float*)d_in[11];
    const int*   sp   = (const int*)d_in[12];
    float* out = (float*)d_out;

    // ws layout (floats). Base 12.92 MB + gch.
    float* ws = (float*)d_ws;
    float* A_  = ws + 0;                 // 786432: qb, later h2b
    float* B_  = ws + 786432;            // 786432: kb, later yp[0..]
    float* C_  = ws + 1572864;           // 786432: vb, later yp[..]
    float* Dd  = ws + 2359296;           // 786432: h, later ab
    float* cb  = ws + 3145728;           // 65536
    float* probs = ws + 3211264;         // 8192
    float* wtok  = ws + 3219456;         // 2048
    int*   list  = (int*)(ws + 3221504); // 8192 ints
    int*   counts= (int*)(ws + 3229696); // 16 ints
    short* gch   = (short*)(ws + 3229712); // 2T*HCuse bf16
    float* yp = B_;                      // 2T*D fp32 (B_ and C_ contiguous)

    // Single-chunk MoE if workspace allows (gch = 2T*HID bf16 = 12.58 MB), else 3 chunks.
    size_t need_big = (size_t)3229712 * 4 + (size_t)2 * T * HID * 2;
    int HCuse = (ws_size >= need_big) ? HID : 1024;

    hipMemsetAsync(counts, 0, 16 * sizeof(int), stream);

    // ---- attention ----
    rmsnorm_kernel<<<T, 256, 0, stream>>>(x, n1w, Dd);                                       // h
    gemm_bf16<false><<<dim3(D / 64, T / 64), 256, 0, stream>>>(Dd, wq, nullptr, A_, T, D, D);    // qb
    gemm_bf16<false><<<dim3(1, T / 64), 256, 0, stream>>>(Dd, wdkv, nullptr, cb, T, DL, D);      // c
    gemm_kuv<<<dim3(D / 64, T / 64), 256, 0, stream>>>(cb, wuk, wuv, B_, C_, T, D, DL);          // kb, vb
    rope_kernel<<<(T * H * 32 + 255) / 256, 256, 0, stream>>>(A_, B_, sp);
    attn_mfma<<<dim3(8, H, BATCH), 256, 0, stream>>>(A_, B_, C_, Dd);                        // ab
    gemm_bf16<true><<<dim3(D / 64, T / 64), 256, 0, stream>>>(Dd, wo, x, out, T, D, D);      // x1 in out

    // ---- MoE ----
    rmsnorm_kernel<<<T, 256, 0, stream>>>(out, n2w, A_);                                     // h2
    routing_kernel<<<T, 64, 0, stream>>>(A_, gw, probs, list, counts, wtok);
    aux_kernel<<<1, 256, 0, stream>>>(probs, counts, out + (out_size - 1));
    for (int c0 = 0; c0 < HID; c0 += HCuse) {
        moe_up_mfma<<<dim3(HCuse / 64, T / 64, E), 256, 0, stream>>>(A_, w1, w3, list, counts, gch, HCuse, c0);
        moe_down_mfma<<<dim3(D / 64, T / 64, E), 256, 0, stream>>>(gch, w2, list, counts, yp, HCuse, c0, c0 == 0 ? 1 : 0);
    }
    combine_kernel<<<(T * (D / 4) + 255) / 256, 256, 0, stream>>>(yp, wtok, out);
}